// Round 15
// baseline (258.035 us; speedup 1.0000x reference)
//
#include <hip/hip_runtime.h>
#include <hip/hip_fp16.h>

#define HWPIX 16384

typedef _Float16 h2 __attribute__((ext_vector_type(2)));
typedef int v2i __attribute__((ext_vector_type(2)));
typedef float f2 __attribute__((ext_vector_type(2)));
typedef float f4 __attribute__((ext_vector_type(4)));

// ---------------------------------------------------------------------------
// ws layout (floats) — NO memset required (all slots fully overwritten):
//   mu     [2048]     @ 0       (ns_all)
//   rsig   [2048]     @ 2048    (ns_all)
//   med    [2048]     @ 4096    (stats)
//   wht    [49152]    @ 6144    (ns_all)
//   rspart [16*2048]  @ 55296   (gram partial row sums, plain stores)
//   gpart  [16*49152] @ 88064   (gram partials per k-chunk, plain stores)
// ---------------------------------------------------------------------------

#define TPAD 130   // halves per tile row: 260B -> dword stride 65 == 1 mod 32 (conflict-free)

template<int J>
__device__ inline unsigned shfl_xor_u(unsigned v, int lane) {
  if constexpr (J == 1)
    return (unsigned)__builtin_amdgcn_mov_dpp((int)v, 0xB1, 0xF, 0xF, true);   // quad_perm 1,0,3,2
  else if constexpr (J == 2)
    return (unsigned)__builtin_amdgcn_mov_dpp((int)v, 0x4E, 0xF, 0xF, true);   // quad_perm 2,3,0,1
  else if constexpr (J == 4)
    return (unsigned)__builtin_amdgcn_ds_swizzle((int)v, 0x101F);
  else if constexpr (J == 8)
    return (unsigned)__builtin_amdgcn_ds_swizzle((int)v, 0x201F);
  else if constexpr (J == 16)
    return (unsigned)__builtin_amdgcn_ds_swizzle((int)v, 0x401F);
  else {
#if __has_builtin(__builtin_amdgcn_permlane32_swap)
    // VALU cross-half swap: res0 upper half = v lower half; res1 lower = v upper.
    v2i r = __builtin_amdgcn_permlane32_swap((int)v, (int)v, false, false);
    return (lane & 32) ? (unsigned)r[0] : (unsigned)r[1];
#else
    return (unsigned)__shfl_xor((int)v, 32);
#endif
  }
}

__device__ inline unsigned pk_min(unsigned a, unsigned b) {
  h2 x = __builtin_bit_cast(h2, a), y = __builtin_bit_cast(h2, b);
  return __builtin_bit_cast(unsigned, __builtin_elementwise_min(x, y));
}
__device__ inline unsigned pk_max(unsigned a, unsigned b) {
  h2 x = __builtin_bit_cast(h2, a), y = __builtin_bit_cast(h2, b);
  return __builtin_bit_cast(unsigned, __builtin_elementwise_max(x, y));
}

// DPP-based 64-lane max reduction step (VALU only, no LDS pipe).
template<int CTRL>
__device__ inline unsigned dppmax(unsigned m) {
  unsigned t = (unsigned)__builtin_amdgcn_update_dpp((int)m, (int)m, CTRL, 0xF, 0xF, false);
  return pk_max(m, t);
}

template<int K, int J, int Q>
__device__ inline void bstep(unsigned (&v0)[Q], unsigned (&v1)[Q], const int lane) {
  const bool sel0 = (((lane & J) == 0) == ((lane & K) == 0));
  const int i1 = lane + 64;
  const bool sel1 = (((i1 & J) == 0) == ((i1 & K) == 0));
  unsigned pv[Q];
  #pragma unroll
  for (int q = 0; q < Q; ++q) pv[q] = shfl_xor_u<J>(v0[q], lane);
  #pragma unroll
  for (int q = 0; q < Q; ++q)
    v0[q] = sel0 ? pk_min(v0[q], pv[q]) : pk_max(v0[q], pv[q]);
  #pragma unroll
  for (int q = 0; q < Q; ++q) pv[q] = shfl_xor_u<J>(v1[q], lane);
  #pragma unroll
  for (int q = 0; q < Q; ++q)
    v1[q] = sel1 ? pk_min(v1[q], pv[q]) : pk_max(v1[q], pv[q]);
  if constexpr (J > 1) bstep<K, J / 2, Q>(v0, v1, lane);
}

// Lower median (rank 63 of 128) per packed column. Stages k=2..64 make the
// sequence bitonic (asc 0-63, desc 64-127); min(v0,v1) isolates the 64
// smallest as a set; their max (DPP reduce -> lane 63) is sorted[63].
template<int Q>
__device__ inline void median128h_low(unsigned (&v0)[Q], unsigned (&v1)[Q],
                                      unsigned (&m)[Q], const int lane) {
  bstep<2, 1, Q>(v0, v1, lane);
  bstep<4, 2, Q>(v0, v1, lane);
  bstep<8, 4, Q>(v0, v1, lane);
  bstep<16, 8, Q>(v0, v1, lane);
  bstep<32, 16, Q>(v0, v1, lane);
  bstep<64, 32, Q>(v0, v1, lane);
  #pragma unroll
  for (int q = 0; q < Q; ++q) m[q] = pk_min(v0[q], v1[q]);
  #pragma unroll
  for (int q = 0; q < Q; ++q) m[q] = dppmax<0x111>(m[q]);  // row_shr:1
  #pragma unroll
  for (int q = 0; q < Q; ++q) m[q] = dppmax<0x112>(m[q]);  // row_shr:2
  #pragma unroll
  for (int q = 0; q < Q; ++q) m[q] = dppmax<0x114>(m[q]);  // row_shr:4
  #pragma unroll
  for (int q = 0; q < Q; ++q) m[q] = dppmax<0x118>(m[q]);  // row_shr:8
  #pragma unroll
  for (int q = 0; q < Q; ++q) m[q] = dppmax<0x142>(m[q]);  // row_bcast:15
  #pragma unroll
  for (int q = 0; q < Q; ++q) m[q] = dppmax<0x143>(m[q]);  // row_bcast:31 -> lane 63
}

template<int CTRL>
__device__ inline float fmax_dpp(float m) {
  float t = __builtin_bit_cast(float,
      __builtin_amdgcn_update_dpp(__builtin_bit_cast(int, m),
                                  __builtin_bit_cast(int, m), CTRL, 0xF, 0xF, false));
  return fmaxf(m, t);
}

// fp32 lower-median-of-128; result valid in lane 63.
__device__ inline float median128f_low(float v0, float v1, const int lane) {
  #pragma unroll
  for (int k = 2; k <= 64; k <<= 1) {
    #pragma unroll
    for (int j = k >> 1; j > 0; j >>= 1) {
      const bool sel0 = (((lane & j) == 0) == ((lane & k) == 0));
      const int i1 = lane + 64;
      const bool sel1 = (((i1 & j) == 0) == ((i1 & k) == 0));
      float pv = __shfl_xor(v0, j);
      v0 = sel0 ? fminf(v0, pv) : fmaxf(v0, pv);
      float pw = __shfl_xor(v1, j);
      v1 = sel1 ? fminf(v1, pw) : fmaxf(v1, pw);
    }
  }
  float m = fminf(v0, v1);
  m = fmax_dpp<0x111>(m); m = fmax_dpp<0x112>(m); m = fmax_dpp<0x114>(m);
  m = fmax_dpp<0x118>(m); m = fmax_dpp<0x142>(m); m = fmax_dpp<0x143>(m);
  return m;  // lane 63
}

// Median-only kernel. One block per (b,c), 512 threads.
__global__ __launch_bounds__(512) void stats_kernel(const float* __restrict__ x,
                                                    float* __restrict__ med) {
  __shared__ __half tile[128 * TPAD];
  __shared__ float colmed[128];

  const int bc = blockIdx.x;
  const int tid = threadIdx.x;
  const float* xp = x + (size_t)bc * HWPIX;

  #pragma unroll
  for (int j = 0; j < 8; ++j) {
    int v = tid + j * 512;            // float4 index 0..4095
    int h = v >> 5;
    int w = (v & 31) * 4;
    float4 val = *reinterpret_cast<const float4*>(xp + (size_t)v * 4);
    __half2* dst = reinterpret_cast<__half2*>(&tile[h * TPAD + w]);
    dst[0] = __floats2half2_rn(val.x, val.y);
    dst[1] = __floats2half2_rn(val.z, val.w);
  }
  __syncthreads();

  const int lane = tid & 63;
  const int wid  = tid >> 6;          // 0..7: wave sorts packed cols wid*8..wid*8+7
  {
    const int w = wid * 16;           // real column base
    unsigned v0[8], v1[8], m[8];
    #pragma unroll
    for (int q = 0; q < 8; ++q) {
      v0[q] = *reinterpret_cast<const unsigned*>(&tile[lane * TPAD + w + 2 * q]);
      v1[q] = *reinterpret_cast<const unsigned*>(&tile[(lane + 64) * TPAD + w + 2 * q]);
    }
    median128h_low<8>(v0, v1, m, lane);
    if (lane == 63) {
      #pragma unroll
      for (int q = 0; q < 8; ++q) {
        h2 mv = __builtin_bit_cast(h2, m[q]);
        colmed[w + 2 * q]     = (float)mv.x;
        colmed[w + 2 * q + 1] = (float)mv.y;
      }
    }
  }
  __syncthreads();
  if (wid == 0) {
    float m = median128f_low(colmed[lane], colmed[lane + 64], lane);
    if (lane == 63) med[bc] = m;
  }
}

// Gram partials + per-channel row-sum partials; plain stores, no atomics.
// grid (16, ngroups, 32); k-chunk = 1024 pixels. Separate kernels per CG so
// each gets its own register budget (grid-fusing them was a 3x regression).
template<int CG>
__global__ __launch_bounds__(256) void gram_kernel(const float* __restrict__ x,
                                                   float* __restrict__ gpart,
                                                   float* __restrict__ rspart) {
  constexpr int QT   = CG / 4;
  constexpr int TPG  = QT * QT;
  constexpr int PQ   = 256 / TPG;
  constexpr int SUBP = 256 / PQ;
  constexpr int THR  = 256 / CG;      // threads per row for rowsum
  __shared__ float tile[CG][260];

  const int b = blockIdx.z;
  const int g = blockIdx.y;
  const int s    = (CG == 16) ? g * 16  : 32;
  const int goff = (CG == 16) ? g * 256 : 512;
  const int chunk = blockIdx.x;
  const int k0 = chunk * 1024;
  const int tid = threadIdx.x;
  const int pq = tid / TPG;
  const int t  = tid % TPG;
  const int ty = t / QT, tx = t % QT;
  const int r0 = ty * 4, c0 = tx * 4;
  const int rrow = tid / THR;
  const int rseg = tid % THR;

  const float* xb = x + (((size_t)(b * 64 + s)) << 14) + k0;
  float acc[4][4] = {};
  float rsum = 0.f;

  for (int sc = 0; sc < 4; ++sc) {
    #pragma unroll
    for (int v = tid; v < CG * 64; v += 256) {
      int r = v >> 6;
      int p4 = (v & 63) * 4;
      *reinterpret_cast<float4*>(&tile[r][p4]) =
          *reinterpret_cast<const float4*>(xb + ((size_t)r << 14) + sc * 256 + p4);
    }
    __syncthreads();
    const int pb0 = pq * SUBP;
    #pragma unroll
    for (int p = pb0; p < pb0 + SUBP; p += 4) {
      float4 a[4], bb[4];
      #pragma unroll
      for (int i = 0; i < 4; ++i) a[i]  = *reinterpret_cast<const float4*>(&tile[r0 + i][p]);
      #pragma unroll
      for (int i = 0; i < 4; ++i) bb[i] = *reinterpret_cast<const float4*>(&tile[c0 + i][p]);
      #pragma unroll
      for (int i = 0; i < 4; ++i)
        #pragma unroll
        for (int j = 0; j < 4; ++j)
          acc[i][j] += a[i].x * bb[j].x + a[i].y * bb[j].y +
                       a[i].z * bb[j].z + a[i].w * bb[j].w;
    }
    // per-channel sum of this 256-px sub-chunk (reads tile inside barrier window)
    #pragma unroll
    for (int i = 0; i < CG / 4; ++i) {
      const float4 v = *reinterpret_cast<const float4*>(&tile[rrow][rseg * CG + i * 4]);
      rsum += v.x + v.y + v.z + v.w;
    }
    __syncthreads();
  }

  #pragma unroll
  for (int j = 1; j < THR; j <<= 1) rsum += __shfl_xor(rsum, j);
  if (rseg == 0) rspart[chunk * 2048 + b * 64 + s + rrow] = rsum;

  float* scratch = reinterpret_cast<float*>(tile);
  #pragma unroll
  for (int i = 0; i < 4; ++i)
    #pragma unroll
    for (int j = 0; j < 4; ++j)
      scratch[(t * PQ + pq) * 16 + i * 4 + j] = acc[i][j];
  __syncthreads();
  if (pq == 0) {
    float* gp = gpart + (size_t)(chunk * 32 + b) * 1536 + goff;
    #pragma unroll
    for (int i = 0; i < 4; ++i)
      #pragma unroll
      for (int j = 0; j < 4; ++j) {
        float v = 0.f;
        for (int q = 0; q < PQ; ++q) v += scratch[(t * PQ + q) * 16 + i * 4 + j];
        gp[(r0 + i) * CG + (c0 + j)] = v;
      }
  }
}

// ------------- Newton-Schulz inverse matrix sqrt (fused 16/32) -------------
template<int CG>
__device__ __forceinline__ void ns_impl(const float* __restrict__ gpart,
                                        const float* __restrict__ rspart,
                                        float* __restrict__ mu,
                                        float* __restrict__ rsig,
                                        float* __restrict__ wht,
                                        const int b, const int g, char* smem) {
  constexpr int NE = CG * CG;
  constexpr int PADC = CG + 4;
  constexpr int MS = CG * PADC;
  float* Y0 = (float*)smem;
  float* Z0 = Y0 + MS;
  float* Y1 = Z0 + MS;
  float* Z1 = Y1 + MS;
  float* T  = Z1 + MS;
  float* red = T + MS;

  const int s    = (CG == 16) ? g * 16  : 32;
  const int goff = (CG == 16) ? g * 256 : 512;
  const int tid = threadIdx.x;
  const float invHW = (float)(1.0 / (16384.0 + 1e-6));

  for (int e = tid; e < NE; e += 256) {
    int r = e / CG, c = e % CG;
    float v = 0.f;
    #pragma unroll
    for (int ch = 0; ch < 16; ++ch)
      v += gpart[(size_t)(ch * 32 + b) * 1536 + goff + e];
    T[r * PADC + c] = v;
  }
  __syncthreads();

  if (tid < CG) {
    float rs = 0.f;
    #pragma unroll
    for (int ch = 0; ch < 16; ++ch) rs += rspart[ch * 2048 + b * 64 + s + tid];
    const float diag = T[tid * PADC + tid];
    const float mean = rs * (1.0f / HWPIX);
    const float var = (diag - rs * mean) / (float)(HWPIX - 1);  // ddof=1
    mu[b * 64 + s + tid] = mean;
    rsig[b * 64 + s + tid] = rsqrtf(var + 1e-6f);
  }
  __syncthreads();

  float ssq = 0.f;
  for (int e = tid; e < NE; e += 256) {
    int r = e / CG, c = e % CG;
    float v = T[r * PADC + c] * invHW + ((r == c) ? 0.001002f : 0.0f);
    T[r * PADC + c] = v;
    ssq += v * v;
  }
  red[tid] = ssq;
  __syncthreads();
  for (int off = 128; off > 0; off >>= 1) {
    if (tid < off) red[tid] += red[tid + off];
    __syncthreads();
  }
  const float cn = sqrtf(red[0]);
  const float icn = 1.0f / cn;
  for (int e = tid; e < NE; e += 256) {
    int r = e / CG, c = e % CG;
    Y0[r * PADC + c] = T[r * PADC + c] * icn;
    Z0[r * PADC + c] = (r == c) ? 1.0f : 0.0f;
  }
  __syncthreads();

  constexpr int ACT = NE / 4;
  const int r  = tid / (CG / 4);
  const int c0 = (tid % (CG / 4)) * 4;

  for (int it = 0; it < 12; ++it) {
    float* Yi = (it & 1) ? Y1 : Y0;
    float* Zi = (it & 1) ? Z1 : Z0;
    float* Yo = (it & 1) ? Y0 : Y1;
    float* Zo = (it & 1) ? Z0 : Z1;
    if (tid < ACT) {
      float ax = 0.f, ay = 0.f, az = 0.f, aw = 0.f;
      #pragma unroll
      for (int k = 0; k < CG; ++k) {
        float zr = Zi[r * PADC + k];
        const float4 yk = *reinterpret_cast<const float4*>(&Yi[k * PADC + c0]);
        ax += zr * yk.x; ay += zr * yk.y; az += zr * yk.z; aw += zr * yk.w;
      }
      float4 tv;
      tv.x = ((r == c0 + 0) ? 3.f : 0.f) - ax;
      tv.y = ((r == c0 + 1) ? 3.f : 0.f) - ay;
      tv.z = ((r == c0 + 2) ? 3.f : 0.f) - az;
      tv.w = ((r == c0 + 3) ? 3.f : 0.f) - aw;
      *reinterpret_cast<float4*>(&T[r * PADC + c0]) = tv;
    }
    __syncthreads();
    if (tid < ACT) {
      float yx = 0.f, yy = 0.f, yz = 0.f, yw = 0.f;
      float zx = 0.f, zy = 0.f, zz = 0.f, zw = 0.f;
      #pragma unroll
      for (int k = 0; k < CG; ++k) {
        float yr = Yi[r * PADC + k];
        float tr = T[r * PADC + k];
        const float4 tk = *reinterpret_cast<const float4*>(&T[k * PADC + c0]);
        const float4 zk = *reinterpret_cast<const float4*>(&Zi[k * PADC + c0]);
        yx += yr * tk.x; yy += yr * tk.y; yz += yr * tk.z; yw += yr * tk.w;
        zx += tr * zk.x; zy += tr * zk.y; zz += tr * zk.z; zw += tr * zk.w;
      }
      *reinterpret_cast<float4*>(&Yo[r * PADC + c0]) =
          make_float4(0.5f * yx, 0.5f * yy, 0.5f * yz, 0.5f * yw);
      *reinterpret_cast<float4*>(&Zo[r * PADC + c0]) =
          make_float4(0.5f * zx, 0.5f * zy, 0.5f * zz, 0.5f * zw);
    }
    __syncthreads();
  }

  const float wscale = rsqrtf(cn);
  for (int e = tid; e < NE; e += 256) {
    int r2 = e / CG, c2 = e % CG;
    wht[b * 1536 + goff + e] = Z0[r2 * PADC + c2] * wscale;
  }
}

__global__ __launch_bounds__(256) void ns_all(const float* __restrict__ gpart,
                                              const float* __restrict__ rspart,
                                              float* __restrict__ mu,
                                              float* __restrict__ rsig,
                                              float* __restrict__ wht) {
  __shared__ __align__(16) char smem[5 * 32 * 36 * 4 + 1024];
  const int bid = blockIdx.x;
  if (bid < 64) ns_impl<16>(gpart, rspart, mu, rsig, wht, bid >> 1, bid & 1, smem);
  else          ns_impl<32>(gpart, rspart, mu, rsig, wht, bid - 64, 0, smem);
}

// --------------- fused whitening-apply + mix + normalize -------------------
// apply16: P=4 pixels/thread (float4) — W LDS-read count per pixel halves.
__global__ __launch_bounds__(256, 2) void apply16(
    const float* __restrict__ x, const float* __restrict__ lmda,
    const int* __restrict__ perm, const float* __restrict__ mu,
    const float* __restrict__ rsig, const float* __restrict__ med,
    const float* __restrict__ wht, float* __restrict__ out) {
  __shared__ float W1[256], W2[256];
  __shared__ float mu1[16], mu2[16], rs1[16], mm[16];

  const int b = blockIdx.z;
  const int g = blockIdx.y;
  const int s = g * 16, goff = g * 256;
  const int tid = threadIdx.x;
  const int pb = perm[b];
  const float lam = lmda[b];
  const float oml = 1.0f - lam;

  if (tid < 256) {
    W1[tid] = wht[b  * 1536 + goff + tid] * lam;
    W2[tid] = wht[pb * 1536 + goff + tid] * oml;
  }
  if (tid < 16) {
    int ch1 = b * 64 + s + tid, ch2 = pb * 64 + s + tid;
    mu1[tid] = mu[ch1];
    mu2[tid] = mu[ch2];
    rs1[tid] = rsig[ch1];
    mm[tid]  = lam * med[ch1] + oml * med[ch2];
  }
  __syncthreads();

  const int p = blockIdx.x * 1024 + tid * 4;
  const float* xb1 = x + (((size_t)(b  * 64 + s)) << 14) + p;
  const float* xb2 = x + (((size_t)(pb * 64 + s)) << 14) + p;
  float* ob = out + (((size_t)(b * 64 + s)) << 14) + p;

  f4 xv1[16], xv2[16];
  #pragma unroll
  for (int d = 0; d < 16; ++d) xv1[d] = *reinterpret_cast<const f4*>(xb1 + ((size_t)d << 14));
  #pragma unroll
  for (int d = 0; d < 16; ++d) xv2[d] = *reinterpret_cast<const f4*>(xb2 + ((size_t)d << 14));
  #pragma unroll
  for (int d = 0; d < 16; ++d) { xv1[d] -= mu1[d]; xv2[d] -= mu2[d]; }

  f4 acc[16] = {};
  #pragma unroll
  for (int d = 0; d < 16; ++d) {
    #pragma unroll
    for (int c = 0; c < 16; ++c) {
      acc[c] += W1[d * 16 + c] * xv1[d];
      acc[c] += W2[d * 16 + c] * xv2[d];
    }
  }
  #pragma unroll
  for (int c = 0; c < 16; ++c) {
    f4 v = xv1[c] * rs1[c] * acc[c] + mm[c];
    __builtin_nontemporal_store(v, reinterpret_cast<f4*>(ob + ((size_t)c << 14)));
  }
}

// apply32: c-half split — each block computes 16 of 32 output channels, so
// per-thread W LDS reads drop 4x (vs monolithic CG=32); x re-read is L2-hit.
__global__ __launch_bounds__(256, 2) void apply32(
    const float* __restrict__ x, const float* __restrict__ lmda,
    const int* __restrict__ perm, const float* __restrict__ mu,
    const float* __restrict__ rsig, const float* __restrict__ med,
    const float* __restrict__ wht, float* __restrict__ out) {
  __shared__ float W1h[512], W2h[512];   // [d][ch] for this half, d*16+ch
  __shared__ float mu1[32], mu2[32], rs1[16], mm[16];

  const int b = blockIdx.z;
  const int h = blockIdx.y;              // c-half: 0 or 1
  const int tid = threadIdx.x;
  const int pb = perm[b];
  const float lam = lmda[b];
  const float oml = 1.0f - lam;

  for (int e = tid; e < 512; e += 256) {
    int d = e >> 4, ch = e & 15;
    W1h[e] = wht[b  * 1536 + 512 + d * 32 + h * 16 + ch] * lam;
    W2h[e] = wht[pb * 1536 + 512 + d * 32 + h * 16 + ch] * oml;
  }
  if (tid < 32) {
    mu1[tid] = mu[b  * 64 + 32 + tid];
    mu2[tid] = mu[pb * 64 + 32 + tid];
  }
  if (tid < 16) {
    int cg = 32 + h * 16 + tid;
    rs1[tid] = rsig[b * 64 + cg];
    mm[tid]  = lam * med[b * 64 + cg] + oml * med[pb * 64 + cg];
  }
  __syncthreads();

  const int p = blockIdx.x * 512 + tid * 2;
  const float* xb1 = x + (((size_t)(b  * 64 + 32)) << 14) + p;
  const float* xb2 = x + (((size_t)(pb * 64 + 32)) << 14) + p;
  float* ob = out + (((size_t)(b * 64 + 32)) << 14) + p;

  f2 xv1[32], xv2[32];
  #pragma unroll
  for (int d = 0; d < 32; ++d) xv1[d] = *reinterpret_cast<const f2*>(xb1 + ((size_t)d << 14));
  #pragma unroll
  for (int d = 0; d < 32; ++d) xv2[d] = *reinterpret_cast<const f2*>(xb2 + ((size_t)d << 14));
  #pragma unroll
  for (int d = 0; d < 32; ++d) { xv1[d] -= mu1[d]; xv2[d] -= mu2[d]; }

  f2 acc[16] = {};
  #pragma unroll
  for (int d = 0; d < 32; ++d) {
    #pragma unroll
    for (int c = 0; c < 16; ++c) {
      acc[c] += W1h[d * 16 + c] * xv1[d];
      acc[c] += W2h[d * 16 + c] * xv2[d];
    }
  }
  #pragma unroll
  for (int c = 0; c < 16; ++c) {
    const int cg = h * 16 + c;           // channel within the 32-group
    f2 v = xv1[cg] * rs1[c] * acc[c] + mm[c];
    __builtin_nontemporal_store(v, reinterpret_cast<f2*>(ob + ((size_t)cg << 14)));
  }
}

extern "C" void kernel_launch(void* const* d_in, const int* in_sizes, int n_in,
                              void* d_out, int out_size, void* d_ws, size_t ws_size,
                              hipStream_t stream) {
  const float* x    = (const float*)d_in[0];
  const float* lmda = (const float*)d_in[1];
  const int*   perm = (const int*)d_in[2];
  float* out = (float*)d_out;
  float* ws  = (float*)d_ws;

  float* mu     = ws;
  float* rsig   = ws + 2048;
  float* med    = ws + 4096;
  float* wht    = ws + 6144;
  float* rspart = ws + 55296;
  float* gpart  = ws + 88064;

  gram_kernel<16><<<dim3(16, 2, 32), 256, 0, stream>>>(x, gpart, rspart);
  gram_kernel<32><<<dim3(16, 1, 32), 256, 0, stream>>>(x, gpart, rspart);

  stats_kernel<<<2048, 512, 0, stream>>>(x, med);

  ns_all<<<96, 256, 0, stream>>>(gpart, rspart, mu, rsig, wht);

  apply16<<<dim3(16, 2, 32), 256, 0, stream>>>(x, lmda, perm, mu, rsig, med, wht, out);
  apply32<<<dim3(32, 2, 32), 256, 0, stream>>>(x, lmda, perm, mu, rsig, med, wht, out);
}

// Round 16
// 247.249 us; speedup vs baseline: 1.0436x; 1.0436x over previous
//
#include <hip/hip_runtime.h>
#include <hip/hip_fp16.h>

#define HWPIX 16384

typedef _Float16 h2 __attribute__((ext_vector_type(2)));
typedef int v2i __attribute__((ext_vector_type(2)));
typedef float f2 __attribute__((ext_vector_type(2)));
typedef float f4 __attribute__((ext_vector_type(4)));

// ---------------------------------------------------------------------------
// ws layout (floats) — NO memset required (all slots fully overwritten):
//   mu     [2048]     @ 0       (ns_all)
//   rsig   [2048]     @ 2048    (ns_all)
//   med    [2048]     @ 4096    (stats)
//   wht    [49152]    @ 6144    (ns_all)
//   rspart [16*2048]  @ 55296   (gram partial row sums, plain stores)
//   gpart  [16*49152] @ 88064   (gram partials per k-chunk, plain stores)
// ---------------------------------------------------------------------------

#define TPAD 130   // halves per tile row: 260B -> dword stride 65 == 1 mod 32 (conflict-free)

template<int J>
__device__ inline unsigned shfl_xor_u(unsigned v, int lane) {
  if constexpr (J == 1)
    return (unsigned)__builtin_amdgcn_mov_dpp((int)v, 0xB1, 0xF, 0xF, true);   // quad_perm 1,0,3,2
  else if constexpr (J == 2)
    return (unsigned)__builtin_amdgcn_mov_dpp((int)v, 0x4E, 0xF, 0xF, true);   // quad_perm 2,3,0,1
  else if constexpr (J == 4)
    return (unsigned)__builtin_amdgcn_ds_swizzle((int)v, 0x101F);
  else if constexpr (J == 8)
    return (unsigned)__builtin_amdgcn_ds_swizzle((int)v, 0x201F);
  else if constexpr (J == 16)
    return (unsigned)__builtin_amdgcn_ds_swizzle((int)v, 0x401F);
  else {
#if __has_builtin(__builtin_amdgcn_permlane32_swap)
    // VALU cross-half swap: res0 upper half = v lower half; res1 lower = v upper.
    v2i r = __builtin_amdgcn_permlane32_swap((int)v, (int)v, false, false);
    return (lane & 32) ? (unsigned)r[0] : (unsigned)r[1];
#else
    return (unsigned)__shfl_xor((int)v, 32);
#endif
  }
}

__device__ inline unsigned pk_min(unsigned a, unsigned b) {
  h2 x = __builtin_bit_cast(h2, a), y = __builtin_bit_cast(h2, b);
  return __builtin_bit_cast(unsigned, __builtin_elementwise_min(x, y));
}
__device__ inline unsigned pk_max(unsigned a, unsigned b) {
  h2 x = __builtin_bit_cast(h2, a), y = __builtin_bit_cast(h2, b);
  return __builtin_bit_cast(unsigned, __builtin_elementwise_max(x, y));
}

// DPP-based 64-lane max reduction step (VALU only, no LDS pipe).
template<int CTRL>
__device__ inline unsigned dppmax(unsigned m) {
  unsigned t = (unsigned)__builtin_amdgcn_update_dpp((int)m, (int)m, CTRL, 0xF, 0xF, false);
  return pk_max(m, t);
}

template<int K, int J, int Q>
__device__ inline void bstep(unsigned (&v0)[Q], unsigned (&v1)[Q], const int lane) {
  const bool sel0 = (((lane & J) == 0) == ((lane & K) == 0));
  const int i1 = lane + 64;
  const bool sel1 = (((i1 & J) == 0) == ((i1 & K) == 0));
  unsigned pv[Q];
  #pragma unroll
  for (int q = 0; q < Q; ++q) pv[q] = shfl_xor_u<J>(v0[q], lane);
  #pragma unroll
  for (int q = 0; q < Q; ++q)
    v0[q] = sel0 ? pk_min(v0[q], pv[q]) : pk_max(v0[q], pv[q]);
  #pragma unroll
  for (int q = 0; q < Q; ++q) pv[q] = shfl_xor_u<J>(v1[q], lane);
  #pragma unroll
  for (int q = 0; q < Q; ++q)
    v1[q] = sel1 ? pk_min(v1[q], pv[q]) : pk_max(v1[q], pv[q]);
  if constexpr (J > 1) bstep<K, J / 2, Q>(v0, v1, lane);
}

// Lower median (rank 63 of 128) per packed column. Stages k=2..64 make the
// sequence bitonic (asc 0-63, desc 64-127); min(v0,v1) isolates the 64
// smallest as a set; their max (DPP reduce -> lane 63) is sorted[63].
template<int Q>
__device__ inline void median128h_low(unsigned (&v0)[Q], unsigned (&v1)[Q],
                                      unsigned (&m)[Q], const int lane) {
  bstep<2, 1, Q>(v0, v1, lane);
  bstep<4, 2, Q>(v0, v1, lane);
  bstep<8, 4, Q>(v0, v1, lane);
  bstep<16, 8, Q>(v0, v1, lane);
  bstep<32, 16, Q>(v0, v1, lane);
  bstep<64, 32, Q>(v0, v1, lane);
  #pragma unroll
  for (int q = 0; q < Q; ++q) m[q] = pk_min(v0[q], v1[q]);
  #pragma unroll
  for (int q = 0; q < Q; ++q) m[q] = dppmax<0x111>(m[q]);  // row_shr:1
  #pragma unroll
  for (int q = 0; q < Q; ++q) m[q] = dppmax<0x112>(m[q]);  // row_shr:2
  #pragma unroll
  for (int q = 0; q < Q; ++q) m[q] = dppmax<0x114>(m[q]);  // row_shr:4
  #pragma unroll
  for (int q = 0; q < Q; ++q) m[q] = dppmax<0x118>(m[q]);  // row_shr:8
  #pragma unroll
  for (int q = 0; q < Q; ++q) m[q] = dppmax<0x142>(m[q]);  // row_bcast:15
  #pragma unroll
  for (int q = 0; q < Q; ++q) m[q] = dppmax<0x143>(m[q]);  // row_bcast:31 -> lane 63
}

template<int CTRL>
__device__ inline float fmax_dpp(float m) {
  float t = __builtin_bit_cast(float,
      __builtin_amdgcn_update_dpp(__builtin_bit_cast(int, m),
                                  __builtin_bit_cast(int, m), CTRL, 0xF, 0xF, false));
  return fmaxf(m, t);
}

// fp32 lower-median-of-128; result valid in lane 63.
__device__ inline float median128f_low(float v0, float v1, const int lane) {
  #pragma unroll
  for (int k = 2; k <= 64; k <<= 1) {
    #pragma unroll
    for (int j = k >> 1; j > 0; j >>= 1) {
      const bool sel0 = (((lane & j) == 0) == ((lane & k) == 0));
      const int i1 = lane + 64;
      const bool sel1 = (((i1 & j) == 0) == ((i1 & k) == 0));
      float pv = __shfl_xor(v0, j);
      v0 = sel0 ? fminf(v0, pv) : fmaxf(v0, pv);
      float pw = __shfl_xor(v1, j);
      v1 = sel1 ? fminf(v1, pw) : fmaxf(v1, pw);
    }
  }
  float m = fminf(v0, v1);
  m = fmax_dpp<0x111>(m); m = fmax_dpp<0x112>(m); m = fmax_dpp<0x114>(m);
  m = fmax_dpp<0x118>(m); m = fmax_dpp<0x142>(m); m = fmax_dpp<0x143>(m);
  return m;  // lane 63
}

// Median-only kernel. One block per (b,c), 512 threads.
__global__ __launch_bounds__(512) void stats_kernel(const float* __restrict__ x,
                                                    float* __restrict__ med) {
  __shared__ __half tile[128 * TPAD];
  __shared__ float colmed[128];

  const int bc = blockIdx.x;
  const int tid = threadIdx.x;
  const float* xp = x + (size_t)bc * HWPIX;

  #pragma unroll
  for (int j = 0; j < 8; ++j) {
    int v = tid + j * 512;            // float4 index 0..4095
    int h = v >> 5;
    int w = (v & 31) * 4;
    float4 val = *reinterpret_cast<const float4*>(xp + (size_t)v * 4);
    __half2* dst = reinterpret_cast<__half2*>(&tile[h * TPAD + w]);
    dst[0] = __floats2half2_rn(val.x, val.y);
    dst[1] = __floats2half2_rn(val.z, val.w);
  }
  __syncthreads();

  const int lane = tid & 63;
  const int wid  = tid >> 6;          // 0..7: wave sorts packed cols wid*8..wid*8+7
  {
    const int w = wid * 16;           // real column base
    unsigned v0[8], v1[8], m[8];
    #pragma unroll
    for (int q = 0; q < 8; ++q) {
      v0[q] = *reinterpret_cast<const unsigned*>(&tile[lane * TPAD + w + 2 * q]);
      v1[q] = *reinterpret_cast<const unsigned*>(&tile[(lane + 64) * TPAD + w + 2 * q]);
    }
    median128h_low<8>(v0, v1, m, lane);
    if (lane == 63) {
      #pragma unroll
      for (int q = 0; q < 8; ++q) {
        h2 mv = __builtin_bit_cast(h2, m[q]);
        colmed[w + 2 * q]     = (float)mv.x;
        colmed[w + 2 * q + 1] = (float)mv.y;
      }
    }
  }
  __syncthreads();
  if (wid == 0) {
    float m = median128f_low(colmed[lane], colmed[lane + 64], lane);
    if (lane == 63) med[bc] = m;
  }
}

// Gram partials + per-channel row-sum partials; plain stores, no atomics.
// grid (16, ngroups, 32); k-chunk = 1024 pixels. Separate kernels per CG so
// each gets its own register budget (grid-fusing them was a 3x regression).
template<int CG>
__global__ __launch_bounds__(256) void gram_kernel(const float* __restrict__ x,
                                                   float* __restrict__ gpart,
                                                   float* __restrict__ rspart) {
  constexpr int QT   = CG / 4;
  constexpr int TPG  = QT * QT;
  constexpr int PQ   = 256 / TPG;
  constexpr int SUBP = 256 / PQ;
  constexpr int THR  = 256 / CG;      // threads per row for rowsum
  __shared__ float tile[CG][260];

  const int b = blockIdx.z;
  const int g = blockIdx.y;
  const int s    = (CG == 16) ? g * 16  : 32;
  const int goff = (CG == 16) ? g * 256 : 512;
  const int chunk = blockIdx.x;
  const int k0 = chunk * 1024;
  const int tid = threadIdx.x;
  const int pq = tid / TPG;
  const int t  = tid % TPG;
  const int ty = t / QT, tx = t % QT;
  const int r0 = ty * 4, c0 = tx * 4;
  const int rrow = tid / THR;
  const int rseg = tid % THR;

  const float* xb = x + (((size_t)(b * 64 + s)) << 14) + k0;
  float acc[4][4] = {};
  float rsum = 0.f;

  for (int sc = 0; sc < 4; ++sc) {
    #pragma unroll
    for (int v = tid; v < CG * 64; v += 256) {
      int r = v >> 6;
      int p4 = (v & 63) * 4;
      *reinterpret_cast<float4*>(&tile[r][p4]) =
          *reinterpret_cast<const float4*>(xb + ((size_t)r << 14) + sc * 256 + p4);
    }
    __syncthreads();
    const int pb0 = pq * SUBP;
    #pragma unroll
    for (int p = pb0; p < pb0 + SUBP; p += 4) {
      float4 a[4], bb[4];
      #pragma unroll
      for (int i = 0; i < 4; ++i) a[i]  = *reinterpret_cast<const float4*>(&tile[r0 + i][p]);
      #pragma unroll
      for (int i = 0; i < 4; ++i) bb[i] = *reinterpret_cast<const float4*>(&tile[c0 + i][p]);
      #pragma unroll
      for (int i = 0; i < 4; ++i)
        #pragma unroll
        for (int j = 0; j < 4; ++j)
          acc[i][j] += a[i].x * bb[j].x + a[i].y * bb[j].y +
                       a[i].z * bb[j].z + a[i].w * bb[j].w;
    }
    // per-channel sum of this 256-px sub-chunk (reads tile inside barrier window)
    #pragma unroll
    for (int i = 0; i < CG / 4; ++i) {
      const float4 v = *reinterpret_cast<const float4*>(&tile[rrow][rseg * CG + i * 4]);
      rsum += v.x + v.y + v.z + v.w;
    }
    __syncthreads();
  }

  #pragma unroll
  for (int j = 1; j < THR; j <<= 1) rsum += __shfl_xor(rsum, j);
  if (rseg == 0) rspart[chunk * 2048 + b * 64 + s + rrow] = rsum;

  float* scratch = reinterpret_cast<float*>(tile);
  #pragma unroll
  for (int i = 0; i < 4; ++i)
    #pragma unroll
    for (int j = 0; j < 4; ++j)
      scratch[(t * PQ + pq) * 16 + i * 4 + j] = acc[i][j];
  __syncthreads();
  if (pq == 0) {
    float* gp = gpart + (size_t)(chunk * 32 + b) * 1536 + goff;
    #pragma unroll
    for (int i = 0; i < 4; ++i)
      #pragma unroll
      for (int j = 0; j < 4; ++j) {
        float v = 0.f;
        for (int q = 0; q < PQ; ++q) v += scratch[(t * PQ + q) * 16 + i * 4 + j];
        gp[(r0 + i) * CG + (c0 + j)] = v;
      }
  }
}

// ------------- Newton-Schulz inverse matrix sqrt (fused 16/32) -------------
template<int CG>
__device__ __forceinline__ void ns_impl(const float* __restrict__ gpart,
                                        const float* __restrict__ rspart,
                                        float* __restrict__ mu,
                                        float* __restrict__ rsig,
                                        float* __restrict__ wht,
                                        const int b, const int g, char* smem) {
  constexpr int NE = CG * CG;
  constexpr int PADC = CG + 4;
  constexpr int MS = CG * PADC;
  float* Y0 = (float*)smem;
  float* Z0 = Y0 + MS;
  float* Y1 = Z0 + MS;
  float* Z1 = Y1 + MS;
  float* T  = Z1 + MS;
  float* red = T + MS;

  const int s    = (CG == 16) ? g * 16  : 32;
  const int goff = (CG == 16) ? g * 256 : 512;
  const int tid = threadIdx.x;
  const float invHW = (float)(1.0 / (16384.0 + 1e-6));

  for (int e = tid; e < NE; e += 256) {
    int r = e / CG, c = e % CG;
    float v = 0.f;
    #pragma unroll
    for (int ch = 0; ch < 16; ++ch)
      v += gpart[(size_t)(ch * 32 + b) * 1536 + goff + e];
    T[r * PADC + c] = v;
  }
  __syncthreads();

  if (tid < CG) {
    float rs = 0.f;
    #pragma unroll
    for (int ch = 0; ch < 16; ++ch) rs += rspart[ch * 2048 + b * 64 + s + tid];
    const float diag = T[tid * PADC + tid];
    const float mean = rs * (1.0f / HWPIX);
    const float var = (diag - rs * mean) / (float)(HWPIX - 1);  // ddof=1
    mu[b * 64 + s + tid] = mean;
    rsig[b * 64 + s + tid] = rsqrtf(var + 1e-6f);
  }
  __syncthreads();

  float ssq = 0.f;
  for (int e = tid; e < NE; e += 256) {
    int r = e / CG, c = e % CG;
    float v = T[r * PADC + c] * invHW + ((r == c) ? 0.001002f : 0.0f);
    T[r * PADC + c] = v;
    ssq += v * v;
  }
  red[tid] = ssq;
  __syncthreads();
  for (int off = 128; off > 0; off >>= 1) {
    if (tid < off) red[tid] += red[tid + off];
    __syncthreads();
  }
  const float cn = sqrtf(red[0]);
  const float icn = 1.0f / cn;
  for (int e = tid; e < NE; e += 256) {
    int r = e / CG, c = e % CG;
    Y0[r * PADC + c] = T[r * PADC + c] * icn;
    Z0[r * PADC + c] = (r == c) ? 1.0f : 0.0f;
  }
  __syncthreads();

  constexpr int ACT = NE / 4;
  const int r  = tid / (CG / 4);
  const int c0 = (tid % (CG / 4)) * 4;

  for (int it = 0; it < 12; ++it) {
    float* Yi = (it & 1) ? Y1 : Y0;
    float* Zi = (it & 1) ? Z1 : Z0;
    float* Yo = (it & 1) ? Y0 : Y1;
    float* Zo = (it & 1) ? Z0 : Z1;
    if (tid < ACT) {
      float ax = 0.f, ay = 0.f, az = 0.f, aw = 0.f;
      #pragma unroll
      for (int k = 0; k < CG; ++k) {
        float zr = Zi[r * PADC + k];
        const float4 yk = *reinterpret_cast<const float4*>(&Yi[k * PADC + c0]);
        ax += zr * yk.x; ay += zr * yk.y; az += zr * yk.z; aw += zr * yk.w;
      }
      float4 tv;
      tv.x = ((r == c0 + 0) ? 3.f : 0.f) - ax;
      tv.y = ((r == c0 + 1) ? 3.f : 0.f) - ay;
      tv.z = ((r == c0 + 2) ? 3.f : 0.f) - az;
      tv.w = ((r == c0 + 3) ? 3.f : 0.f) - aw;
      *reinterpret_cast<float4*>(&T[r * PADC + c0]) = tv;
    }
    __syncthreads();
    if (tid < ACT) {
      float yx = 0.f, yy = 0.f, yz = 0.f, yw = 0.f;
      float zx = 0.f, zy = 0.f, zz = 0.f, zw = 0.f;
      #pragma unroll
      for (int k = 0; k < CG; ++k) {
        float yr = Yi[r * PADC + k];
        float tr = T[r * PADC + k];
        const float4 tk = *reinterpret_cast<const float4*>(&T[k * PADC + c0]);
        const float4 zk = *reinterpret_cast<const float4*>(&Zi[k * PADC + c0]);
        yx += yr * tk.x; yy += yr * tk.y; yz += yr * tk.z; yw += yr * tk.w;
        zx += tr * zk.x; zy += tr * zk.y; zz += tr * zk.z; zw += tr * zk.w;
      }
      *reinterpret_cast<float4*>(&Yo[r * PADC + c0]) =
          make_float4(0.5f * yx, 0.5f * yy, 0.5f * yz, 0.5f * yw);
      *reinterpret_cast<float4*>(&Zo[r * PADC + c0]) =
          make_float4(0.5f * zx, 0.5f * zy, 0.5f * zz, 0.5f * zw);
    }
    __syncthreads();
  }

  const float wscale = rsqrtf(cn);
  for (int e = tid; e < NE; e += 256) {
    int r2 = e / CG, c2 = e % CG;
    wht[b * 1536 + goff + e] = Z0[r2 * PADC + c2] * wscale;
  }
}

__global__ __launch_bounds__(256) void ns_all(const float* __restrict__ gpart,
                                              const float* __restrict__ rspart,
                                              float* __restrict__ mu,
                                              float* __restrict__ rsig,
                                              float* __restrict__ wht) {
  __shared__ __align__(16) char smem[5 * 32 * 36 * 4 + 1024];
  const int bid = blockIdx.x;
  if (bid < 64) ns_impl<16>(gpart, rspart, mu, rsig, wht, bid >> 1, bid & 1, smem);
  else          ns_impl<32>(gpart, rspart, mu, rsig, wht, bid - 64, 0, smem);
}

// --------------- fused whitening-apply + mix + normalize -------------------
// apply16: P=4 pixels/thread (float4) — W LDS-read count per pixel halves.
__global__ __launch_bounds__(256, 2) void apply16(
    const float* __restrict__ x, const float* __restrict__ lmda,
    const int* __restrict__ perm, const float* __restrict__ mu,
    const float* __restrict__ rsig, const float* __restrict__ med,
    const float* __restrict__ wht, float* __restrict__ out) {
  __shared__ float W1[256], W2[256];
  __shared__ float mu1[16], mu2[16], rs1[16], mm[16];

  const int b = blockIdx.z;
  const int g = blockIdx.y;
  const int s = g * 16, goff = g * 256;
  const int tid = threadIdx.x;
  const int pb = perm[b];
  const float lam = lmda[b];
  const float oml = 1.0f - lam;

  if (tid < 256) {
    W1[tid] = wht[b  * 1536 + goff + tid] * lam;
    W2[tid] = wht[pb * 1536 + goff + tid] * oml;
  }
  if (tid < 16) {
    int ch1 = b * 64 + s + tid, ch2 = pb * 64 + s + tid;
    mu1[tid] = mu[ch1];
    mu2[tid] = mu[ch2];
    rs1[tid] = rsig[ch1];
    mm[tid]  = lam * med[ch1] + oml * med[ch2];
  }
  __syncthreads();

  const int p = blockIdx.x * 1024 + tid * 4;
  const float* xb1 = x + (((size_t)(b  * 64 + s)) << 14) + p;
  const float* xb2 = x + (((size_t)(pb * 64 + s)) << 14) + p;
  float* ob = out + (((size_t)(b * 64 + s)) << 14) + p;

  f4 xv1[16], xv2[16];
  #pragma unroll
  for (int d = 0; d < 16; ++d) xv1[d] = *reinterpret_cast<const f4*>(xb1 + ((size_t)d << 14));
  #pragma unroll
  for (int d = 0; d < 16; ++d) xv2[d] = *reinterpret_cast<const f4*>(xb2 + ((size_t)d << 14));
  #pragma unroll
  for (int d = 0; d < 16; ++d) { xv1[d] -= mu1[d]; xv2[d] -= mu2[d]; }

  f4 acc[16] = {};
  #pragma unroll
  for (int d = 0; d < 16; ++d) {
    #pragma unroll
    for (int c = 0; c < 16; ++c) {
      acc[c] += W1[d * 16 + c] * xv1[d];
      acc[c] += W2[d * 16 + c] * xv2[d];
    }
  }
  #pragma unroll
  for (int c = 0; c < 16; ++c) {
    f4 v = xv1[c] * rs1[c] * acc[c] + mm[c];
    __builtin_nontemporal_store(v, reinterpret_cast<f4*>(ob + ((size_t)c << 14)));
  }
}

// apply32: monolithic CG=32, P=2 pixels/thread — each x element read exactly
// once (the c-half split doubled HBM reads and was 2.7x slower).
__global__ __launch_bounds__(256, 2) void apply32(
    const float* __restrict__ x, const float* __restrict__ lmda,
    const int* __restrict__ perm, const float* __restrict__ mu,
    const float* __restrict__ rsig, const float* __restrict__ med,
    const float* __restrict__ wht, float* __restrict__ out) {
  __shared__ float W1[1024], W2[1024];
  __shared__ float mu1[32], mu2[32], rs1[32], mm[32];

  const int b = blockIdx.z;
  const int tid = threadIdx.x;
  const int pb = perm[b];
  const float lam = lmda[b];
  const float oml = 1.0f - lam;

  for (int e = tid; e < 1024; e += 256) {
    W1[e] = wht[b  * 1536 + 512 + e] * lam;
    W2[e] = wht[pb * 1536 + 512 + e] * oml;
  }
  if (tid < 32) {
    int ch1 = b * 64 + 32 + tid, ch2 = pb * 64 + 32 + tid;
    mu1[tid] = mu[ch1];
    mu2[tid] = mu[ch2];
    rs1[tid] = rsig[ch1];
    mm[tid]  = lam * med[ch1] + oml * med[ch2];
  }
  __syncthreads();

  const int p = blockIdx.x * 512 + tid * 2;
  const float* xb1 = x + (((size_t)(b  * 64 + 32)) << 14) + p;
  const float* xb2 = x + (((size_t)(pb * 64 + 32)) << 14) + p;
  float* ob = out + (((size_t)(b * 64 + 32)) << 14) + p;

  f2 xv1[32], xv2[32];
  #pragma unroll
  for (int d = 0; d < 32; ++d) xv1[d] = *reinterpret_cast<const f2*>(xb1 + ((size_t)d << 14));
  #pragma unroll
  for (int d = 0; d < 32; ++d) xv2[d] = *reinterpret_cast<const f2*>(xb2 + ((size_t)d << 14));
  #pragma unroll
  for (int d = 0; d < 32; ++d) { xv1[d] -= mu1[d]; xv2[d] -= mu2[d]; }

  f2 acc[32] = {};
  #pragma unroll
  for (int d = 0; d < 32; ++d) {
    #pragma unroll
    for (int c = 0; c < 32; ++c) {
      acc[c] += W1[d * 32 + c] * xv1[d];
      acc[c] += W2[d * 32 + c] * xv2[d];
    }
  }
  #pragma unroll
  for (int c = 0; c < 32; ++c) {
    f2 v = xv1[c] * rs1[c] * acc[c] + mm[c];
    __builtin_nontemporal_store(v, reinterpret_cast<f2*>(ob + ((size_t)c << 14)));
  }
}

extern "C" void kernel_launch(void* const* d_in, const int* in_sizes, int n_in,
                              void* d_out, int out_size, void* d_ws, size_t ws_size,
                              hipStream_t stream) {
  const float* x    = (const float*)d_in[0];
  const float* lmda = (const float*)d_in[1];
  const int*   perm = (const int*)d_in[2];
  float* out = (float*)d_out;
  float* ws  = (float*)d_ws;

  float* mu     = ws;
  float* rsig   = ws + 2048;
  float* med    = ws + 4096;
  float* wht    = ws + 6144;
  float* rspart = ws + 55296;
  float* gpart  = ws + 88064;

  gram_kernel<16><<<dim3(16, 2, 32), 256, 0, stream>>>(x, gpart, rspart);
  gram_kernel<32><<<dim3(16, 1, 32), 256, 0, stream>>>(x, gpart, rspart);

  stats_kernel<<<2048, 512, 0, stream>>>(x, med);

  ns_all<<<96, 256, 0, stream>>>(gpart, rspart, mu, rsig, wht);

  apply16<<<dim3(16, 2, 32), 256, 0, stream>>>(x, lmda, perm, mu, rsig, med, wht, out);
  apply32<<<dim3(32, 1, 32), 256, 0, stream>>>(x, lmda, perm, mu, rsig, med, wht, out);
}

// Round 17
// 223.996 us; speedup vs baseline: 1.1520x; 1.1038x over previous
//
#include <hip/hip_runtime.h>
#include <hip/hip_fp16.h>

#define HWPIX 16384

typedef _Float16 h2 __attribute__((ext_vector_type(2)));
typedef int v2i __attribute__((ext_vector_type(2)));
typedef float f2 __attribute__((ext_vector_type(2)));
typedef float f4 __attribute__((ext_vector_type(4)));

// ---------------------------------------------------------------------------
// ws layout (floats) — NO memset required (all slots fully overwritten):
//   mu     [2048]     @ 0       (ns_all)
//   rsig   [2048]     @ 2048    (ns_all)
//   med    [2048]     @ 4096    (stats)
//   wht    [49152]    @ 6144    (ns_all)
//   rspart [16*2048]  @ 55296   (gram partial row sums, plain stores)
//   gpart  [16*49152] @ 88064   (gram partials per k-chunk, plain stores)
// ---------------------------------------------------------------------------

template<int J>
__device__ inline unsigned shfl_xor_u(unsigned v, int lane) {
  if constexpr (J == 1)
    return (unsigned)__builtin_amdgcn_mov_dpp((int)v, 0xB1, 0xF, 0xF, true);   // quad_perm 1,0,3,2
  else if constexpr (J == 2)
    return (unsigned)__builtin_amdgcn_mov_dpp((int)v, 0x4E, 0xF, 0xF, true);   // quad_perm 2,3,0,1
  else if constexpr (J == 4)
    return (unsigned)__builtin_amdgcn_ds_swizzle((int)v, 0x101F);
  else if constexpr (J == 8)
    return (unsigned)__builtin_amdgcn_ds_swizzle((int)v, 0x201F);
  else if constexpr (J == 16)
    return (unsigned)__builtin_amdgcn_ds_swizzle((int)v, 0x401F);
  else {
#if __has_builtin(__builtin_amdgcn_permlane32_swap)
    // VALU cross-half swap: res0 upper half = v lower half; res1 lower = v upper.
    v2i r = __builtin_amdgcn_permlane32_swap((int)v, (int)v, false, false);
    return (lane & 32) ? (unsigned)r[0] : (unsigned)r[1];
#else
    return (unsigned)__shfl_xor((int)v, 32);
#endif
  }
}

__device__ inline unsigned pk_min(unsigned a, unsigned b) {
  h2 x = __builtin_bit_cast(h2, a), y = __builtin_bit_cast(h2, b);
  return __builtin_bit_cast(unsigned, __builtin_elementwise_min(x, y));
}
__device__ inline unsigned pk_max(unsigned a, unsigned b) {
  h2 x = __builtin_bit_cast(h2, a), y = __builtin_bit_cast(h2, b);
  return __builtin_bit_cast(unsigned, __builtin_elementwise_max(x, y));
}

__device__ inline unsigned pack2(float x, float y) {
  h2 p = {(_Float16)x, (_Float16)y};
  return __builtin_bit_cast(unsigned, p);
}

// DPP-based 64-lane max reduction step (VALU only, no LDS pipe).
template<int CTRL>
__device__ inline unsigned dppmax(unsigned m) {
  unsigned t = (unsigned)__builtin_amdgcn_update_dpp((int)m, (int)m, CTRL, 0xF, 0xF, false);
  return pk_max(m, t);
}

template<int K, int J, int Q>
__device__ inline void bstep(unsigned (&v0)[Q], unsigned (&v1)[Q], const int lane) {
  const bool sel0 = (((lane & J) == 0) == ((lane & K) == 0));
  const int i1 = lane + 64;
  const bool sel1 = (((i1 & J) == 0) == ((i1 & K) == 0));
  unsigned pv[Q];
  #pragma unroll
  for (int q = 0; q < Q; ++q) pv[q] = shfl_xor_u<J>(v0[q], lane);
  #pragma unroll
  for (int q = 0; q < Q; ++q)
    v0[q] = sel0 ? pk_min(v0[q], pv[q]) : pk_max(v0[q], pv[q]);
  #pragma unroll
  for (int q = 0; q < Q; ++q) pv[q] = shfl_xor_u<J>(v1[q], lane);
  #pragma unroll
  for (int q = 0; q < Q; ++q)
    v1[q] = sel1 ? pk_min(v1[q], pv[q]) : pk_max(v1[q], pv[q]);
  if constexpr (J > 1) bstep<K, J / 2, Q>(v0, v1, lane);
}

// Lower median (rank 63 of 128) per packed column. Stages k=2..64 make the
// sequence bitonic (asc 0-63, desc 64-127); min(v0,v1) isolates the 64
// smallest as a set; their max (DPP reduce -> lane 63) is sorted[63].
template<int Q>
__device__ inline void median128h_low(unsigned (&v0)[Q], unsigned (&v1)[Q],
                                      unsigned (&m)[Q], const int lane) {
  bstep<2, 1, Q>(v0, v1, lane);
  bstep<4, 2, Q>(v0, v1, lane);
  bstep<8, 4, Q>(v0, v1, lane);
  bstep<16, 8, Q>(v0, v1, lane);
  bstep<32, 16, Q>(v0, v1, lane);
  bstep<64, 32, Q>(v0, v1, lane);
  #pragma unroll
  for (int q = 0; q < Q; ++q) m[q] = pk_min(v0[q], v1[q]);
  #pragma unroll
  for (int q = 0; q < Q; ++q) m[q] = dppmax<0x111>(m[q]);  // row_shr:1
  #pragma unroll
  for (int q = 0; q < Q; ++q) m[q] = dppmax<0x112>(m[q]);  // row_shr:2
  #pragma unroll
  for (int q = 0; q < Q; ++q) m[q] = dppmax<0x114>(m[q]);  // row_shr:4
  #pragma unroll
  for (int q = 0; q < Q; ++q) m[q] = dppmax<0x118>(m[q]);  // row_shr:8
  #pragma unroll
  for (int q = 0; q < Q; ++q) m[q] = dppmax<0x142>(m[q]);  // row_bcast:15
  #pragma unroll
  for (int q = 0; q < Q; ++q) m[q] = dppmax<0x143>(m[q]);  // row_bcast:31 -> lane 63
}

template<int CTRL>
__device__ inline float fmax_dpp(float m) {
  float t = __builtin_bit_cast(float,
      __builtin_amdgcn_update_dpp(__builtin_bit_cast(int, m),
                                  __builtin_bit_cast(int, m), CTRL, 0xF, 0xF, false));
  return fmaxf(m, t);
}

// fp32 lower-median-of-128; result valid in lane 63.
__device__ inline float median128f_low(float v0, float v1, const int lane) {
  #pragma unroll
  for (int k = 2; k <= 64; k <<= 1) {
    #pragma unroll
    for (int j = k >> 1; j > 0; j >>= 1) {
      const bool sel0 = (((lane & j) == 0) == ((lane & k) == 0));
      const int i1 = lane + 64;
      const bool sel1 = (((i1 & j) == 0) == ((i1 & k) == 0));
      float pv = __shfl_xor(v0, j);
      v0 = sel0 ? fminf(v0, pv) : fmaxf(v0, pv);
      float pw = __shfl_xor(v1, j);
      v1 = sel1 ? fminf(v1, pw) : fmaxf(v1, pw);
    }
  }
  float m = fminf(v0, v1);
  m = fmax_dpp<0x111>(m); m = fmax_dpp<0x112>(m); m = fmax_dpp<0x114>(m);
  m = fmax_dpp<0x118>(m); m = fmax_dpp<0x142>(m); m = fmax_dpp<0x143>(m);
  return m;  // lane 63
}

// Median-only kernel, LDS-tile-free: lane l of wave w loads floats
// [w*32, w*32+32) of rows l and l+64 directly (full 128B line per row),
// packs to fp16x2 in registers, runs two 16-column sort batches.
// One block per (b,c), 256 threads (4 waves x 32 columns).
__global__ __launch_bounds__(256) void stats_kernel(const float* __restrict__ x,
                                                    float* __restrict__ med) {
  __shared__ float colmed[128];

  const int bc = blockIdx.x;
  const int tid = threadIdx.x;
  const int lane = tid & 63;
  const int wid  = tid >> 6;          // 0..3
  const float* rowA = x + (size_t)bc * HWPIX + (size_t)lane * 128 + wid * 32;
  const float* rowB = rowA + (size_t)64 * 128;

  unsigned a[16], b[16];              // 32 columns packed, rows lane / lane+64
  #pragma unroll
  for (int i = 0; i < 8; ++i) {
    f4 va = *reinterpret_cast<const f4*>(rowA + i * 4);
    f4 vb = *reinterpret_cast<const f4*>(rowB + i * 4);
    a[2 * i]     = pack2(va.x, va.y);
    a[2 * i + 1] = pack2(va.z, va.w);
    b[2 * i]     = pack2(vb.x, vb.y);
    b[2 * i + 1] = pack2(vb.z, vb.w);
  }

  #pragma unroll
  for (int t = 0; t < 2; ++t) {
    unsigned v0[8], v1[8], m[8];
    #pragma unroll
    for (int q = 0; q < 8; ++q) { v0[q] = a[t * 8 + q]; v1[q] = b[t * 8 + q]; }
    median128h_low<8>(v0, v1, m, lane);
    if (lane == 63) {
      const int base = wid * 32 + t * 16;
      #pragma unroll
      for (int q = 0; q < 8; ++q) {
        h2 mv = __builtin_bit_cast(h2, m[q]);
        colmed[base + 2 * q]     = (float)mv.x;
        colmed[base + 2 * q + 1] = (float)mv.y;
      }
    }
  }
  __syncthreads();
  if (wid == 0) {
    float m = median128f_low(colmed[lane], colmed[lane + 64], lane);
    if (lane == 63) med[bc] = m;
  }
}

// Gram partials + per-channel row-sum partials; plain stores, no atomics.
// grid (16, ngroups, 32); k-chunk = 1024 pixels. Separate kernels per CG so
// each gets its own register budget (grid-fusing them was a 3x regression).
template<int CG>
__global__ __launch_bounds__(256) void gram_kernel(const float* __restrict__ x,
                                                   float* __restrict__ gpart,
                                                   float* __restrict__ rspart) {
  constexpr int QT   = CG / 4;
  constexpr int TPG  = QT * QT;
  constexpr int PQ   = 256 / TPG;
  constexpr int SUBP = 256 / PQ;
  constexpr int THR  = 256 / CG;      // threads per row for rowsum
  __shared__ float tile[CG][260];

  const int b = blockIdx.z;
  const int g = blockIdx.y;
  const int s    = (CG == 16) ? g * 16  : 32;
  const int goff = (CG == 16) ? g * 256 : 512;
  const int chunk = blockIdx.x;
  const int k0 = chunk * 1024;
  const int tid = threadIdx.x;
  const int pq = tid / TPG;
  const int t  = tid % TPG;
  const int ty = t / QT, tx = t % QT;
  const int r0 = ty * 4, c0 = tx * 4;
  const int rrow = tid / THR;
  const int rseg = tid % THR;

  const float* xb = x + (((size_t)(b * 64 + s)) << 14) + k0;
  float acc[4][4] = {};
  float rsum = 0.f;

  for (int sc = 0; sc < 4; ++sc) {
    #pragma unroll
    for (int v = tid; v < CG * 64; v += 256) {
      int r = v >> 6;
      int p4 = (v & 63) * 4;
      *reinterpret_cast<float4*>(&tile[r][p4]) =
          *reinterpret_cast<const float4*>(xb + ((size_t)r << 14) + sc * 256 + p4);
    }
    __syncthreads();
    const int pb0 = pq * SUBP;
    #pragma unroll
    for (int p = pb0; p < pb0 + SUBP; p += 4) {
      float4 a[4], bb[4];
      #pragma unroll
      for (int i = 0; i < 4; ++i) a[i]  = *reinterpret_cast<const float4*>(&tile[r0 + i][p]);
      #pragma unroll
      for (int i = 0; i < 4; ++i) bb[i] = *reinterpret_cast<const float4*>(&tile[c0 + i][p]);
      #pragma unroll
      for (int i = 0; i < 4; ++i)
        #pragma unroll
        for (int j = 0; j < 4; ++j)
          acc[i][j] += a[i].x * bb[j].x + a[i].y * bb[j].y +
                       a[i].z * bb[j].z + a[i].w * bb[j].w;
    }
    // per-channel sum of this 256-px sub-chunk (reads tile inside barrier window)
    #pragma unroll
    for (int i = 0; i < CG / 4; ++i) {
      const float4 v = *reinterpret_cast<const float4*>(&tile[rrow][rseg * CG + i * 4]);
      rsum += v.x + v.y + v.z + v.w;
    }
    __syncthreads();
  }

  #pragma unroll
  for (int j = 1; j < THR; j <<= 1) rsum += __shfl_xor(rsum, j);
  if (rseg == 0) rspart[chunk * 2048 + b * 64 + s + rrow] = rsum;

  float* scratch = reinterpret_cast<float*>(tile);
  #pragma unroll
  for (int i = 0; i < 4; ++i)
    #pragma unroll
    for (int j = 0; j < 4; ++j)
      scratch[(t * PQ + pq) * 16 + i * 4 + j] = acc[i][j];
  __syncthreads();
  if (pq == 0) {
    float* gp = gpart + (size_t)(chunk * 32 + b) * 1536 + goff;
    #pragma unroll
    for (int i = 0; i < 4; ++i)
      #pragma unroll
      for (int j = 0; j < 4; ++j) {
        float v = 0.f;
        for (int q = 0; q < PQ; ++q) v += scratch[(t * PQ + q) * 16 + i * 4 + j];
        gp[(r0 + i) * CG + (c0 + j)] = v;
      }
  }
}

// ------------- Newton-Schulz inverse matrix sqrt (fused 16/32) -------------
template<int CG>
__device__ __forceinline__ void ns_impl(const float* __restrict__ gpart,
                                        const float* __restrict__ rspart,
                                        float* __restrict__ mu,
                                        float* __restrict__ rsig,
                                        float* __restrict__ wht,
                                        const int b, const int g, char* smem) {
  constexpr int NE = CG * CG;
  constexpr int PADC = CG + 4;
  constexpr int MS = CG * PADC;
  float* Y0 = (float*)smem;
  float* Z0 = Y0 + MS;
  float* Y1 = Z0 + MS;
  float* Z1 = Y1 + MS;
  float* T  = Z1 + MS;
  float* red = T + MS;

  const int s    = (CG == 16) ? g * 16  : 32;
  const int goff = (CG == 16) ? g * 256 : 512;
  const int tid = threadIdx.x;
  const float invHW = (float)(1.0 / (16384.0 + 1e-6));

  for (int e = tid; e < NE; e += 256) {
    int r = e / CG, c = e % CG;
    float v = 0.f;
    #pragma unroll
    for (int ch = 0; ch < 16; ++ch)
      v += gpart[(size_t)(ch * 32 + b) * 1536 + goff + e];
    T[r * PADC + c] = v;
  }
  __syncthreads();

  if (tid < CG) {
    float rs = 0.f;
    #pragma unroll
    for (int ch = 0; ch < 16; ++ch) rs += rspart[ch * 2048 + b * 64 + s + tid];
    const float diag = T[tid * PADC + tid];
    const float mean = rs * (1.0f / HWPIX);
    const float var = (diag - rs * mean) / (float)(HWPIX - 1);  // ddof=1
    mu[b * 64 + s + tid] = mean;
    rsig[b * 64 + s + tid] = rsqrtf(var + 1e-6f);
  }
  __syncthreads();

  float ssq = 0.f;
  for (int e = tid; e < NE; e += 256) {
    int r = e / CG, c = e % CG;
    float v = T[r * PADC + c] * invHW + ((r == c) ? 0.001002f : 0.0f);
    T[r * PADC + c] = v;
    ssq += v * v;
  }
  red[tid] = ssq;
  __syncthreads();
  for (int off = 128; off > 0; off >>= 1) {
    if (tid < off) red[tid] += red[tid + off];
    __syncthreads();
  }
  const float cn = sqrtf(red[0]);
  const float icn = 1.0f / cn;
  for (int e = tid; e < NE; e += 256) {
    int r = e / CG, c = e % CG;
    Y0[r * PADC + c] = T[r * PADC + c] * icn;
    Z0[r * PADC + c] = (r == c) ? 1.0f : 0.0f;
  }
  __syncthreads();

  constexpr int ACT = NE / 4;
  const int r  = tid / (CG / 4);
  const int c0 = (tid % (CG / 4)) * 4;

  for (int it = 0; it < 12; ++it) {
    float* Yi = (it & 1) ? Y1 : Y0;
    float* Zi = (it & 1) ? Z1 : Z0;
    float* Yo = (it & 1) ? Y0 : Y1;
    float* Zo = (it & 1) ? Z0 : Z1;
    if (tid < ACT) {
      float ax = 0.f, ay = 0.f, az = 0.f, aw = 0.f;
      #pragma unroll
      for (int k = 0; k < CG; ++k) {
        float zr = Zi[r * PADC + k];
        const float4 yk = *reinterpret_cast<const float4*>(&Yi[k * PADC + c0]);
        ax += zr * yk.x; ay += zr * yk.y; az += zr * yk.z; aw += zr * yk.w;
      }
      float4 tv;
      tv.x = ((r == c0 + 0) ? 3.f : 0.f) - ax;
      tv.y = ((r == c0 + 1) ? 3.f : 0.f) - ay;
      tv.z = ((r == c0 + 2) ? 3.f : 0.f) - az;
      tv.w = ((r == c0 + 3) ? 3.f : 0.f) - aw;
      *reinterpret_cast<float4*>(&T[r * PADC + c0]) = tv;
    }
    __syncthreads();
    if (tid < ACT) {
      float yx = 0.f, yy = 0.f, yz = 0.f, yw = 0.f;
      float zx = 0.f, zy = 0.f, zz = 0.f, zw = 0.f;
      #pragma unroll
      for (int k = 0; k < CG; ++k) {
        float yr = Yi[r * PADC + k];
        float tr = T[r * PADC + k];
        const float4 tk = *reinterpret_cast<const float4*>(&T[k * PADC + c0]);
        const float4 zk = *reinterpret_cast<const float4*>(&Zi[k * PADC + c0]);
        yx += yr * tk.x; yy += yr * tk.y; yz += yr * tk.z; yw += yr * tk.w;
        zx += tr * zk.x; zy += tr * zk.y; zz += tr * zk.z; zw += tr * zk.w;
      }
      *reinterpret_cast<float4*>(&Yo[r * PADC + c0]) =
          make_float4(0.5f * yx, 0.5f * yy, 0.5f * yz, 0.5f * yw);
      *reinterpret_cast<float4*>(&Zo[r * PADC + c0]) =
          make_float4(0.5f * zx, 0.5f * zy, 0.5f * zz, 0.5f * zw);
    }
    __syncthreads();
  }

  const float wscale = rsqrtf(cn);
  for (int e = tid; e < NE; e += 256) {
    int r2 = e / CG, c2 = e % CG;
    wht[b * 1536 + goff + e] = Z0[r2 * PADC + c2] * wscale;
  }
}

__global__ __launch_bounds__(256) void ns_all(const float* __restrict__ gpart,
                                              const float* __restrict__ rspart,
                                              float* __restrict__ mu,
                                              float* __restrict__ rsig,
                                              float* __restrict__ wht) {
  __shared__ __align__(16) char smem[5 * 32 * 36 * 4 + 1024];
  const int bid = blockIdx.x;
  if (bid < 64) ns_impl<16>(gpart, rspart, mu, rsig, wht, bid >> 1, bid & 1, smem);
  else          ns_impl<32>(gpart, rspart, mu, rsig, wht, bid - 64, 0, smem);
}

// --------------- fused whitening-apply + mix + normalize -------------------
// apply16: CG=16, P=2 pixels/thread (round-14 best config).
__global__ __launch_bounds__(256, 4) void apply16(
    const float* __restrict__ x, const float* __restrict__ lmda,
    const int* __restrict__ perm, const float* __restrict__ mu,
    const float* __restrict__ rsig, const float* __restrict__ med,
    const float* __restrict__ wht, float* __restrict__ out) {
  __shared__ float W1[256], W2[256];
  __shared__ float mu1[16], mu2[16], rs1[16], mm[16];

  const int b = blockIdx.z;
  const int g = blockIdx.y;
  const int s = g * 16, goff = g * 256;
  const int tid = threadIdx.x;
  const int pb = perm[b];
  const float lam = lmda[b];
  const float oml = 1.0f - lam;

  if (tid < 256) {
    W1[tid] = wht[b  * 1536 + goff + tid] * lam;
    W2[tid] = wht[pb * 1536 + goff + tid] * oml;
  }
  if (tid < 16) {
    int ch1 = b * 64 + s + tid, ch2 = pb * 64 + s + tid;
    mu1[tid] = mu[ch1];
    mu2[tid] = mu[ch2];
    rs1[tid] = rsig[ch1];
    mm[tid]  = lam * med[ch1] + oml * med[ch2];
  }
  __syncthreads();

  const int p = blockIdx.x * 512 + tid * 2;
  const float* xb1 = x + (((size_t)(b  * 64 + s)) << 14) + p;
  const float* xb2 = x + (((size_t)(pb * 64 + s)) << 14) + p;
  float* ob = out + (((size_t)(b * 64 + s)) << 14) + p;

  f2 xv1[16], xv2[16];
  #pragma unroll
  for (int d = 0; d < 16; ++d) xv1[d] = *reinterpret_cast<const f2*>(xb1 + ((size_t)d << 14));
  #pragma unroll
  for (int d = 0; d < 16; ++d) xv2[d] = *reinterpret_cast<const f2*>(xb2 + ((size_t)d << 14));
  #pragma unroll
  for (int d = 0; d < 16; ++d) { xv1[d] -= mu1[d]; xv2[d] -= mu2[d]; }

  f2 acc[16] = {};
  #pragma unroll
  for (int d = 0; d < 16; ++d) {
    #pragma unroll
    for (int c = 0; c < 16; ++c) {
      acc[c] += W1[d * 16 + c] * xv1[d];
      acc[c] += W2[d * 16 + c] * xv2[d];
    }
  }
  #pragma unroll
  for (int c = 0; c < 16; ++c) {
    f2 v = xv1[c] * rs1[c] * acc[c] + mm[c];
    __builtin_nontemporal_store(v, reinterpret_cast<f2*>(ob + ((size_t)c << 14)));
  }
}

// apply32: monolithic CG=32, P=2 pixels/thread — each x element read exactly
// once (the c-half split doubled HBM reads and was 2.7x slower).
__global__ __launch_bounds__(256, 2) void apply32(
    const float* __restrict__ x, const float* __restrict__ lmda,
    const int* __restrict__ perm, const float* __restrict__ mu,
    const float* __restrict__ rsig, const float* __restrict__ med,
    const float* __restrict__ wht, float* __restrict__ out) {
  __shared__ float W1[1024], W2[1024];
  __shared__ float mu1[32], mu2[32], rs1[32], mm[32];

  const int b = blockIdx.z;
  const int tid = threadIdx.x;
  const int pb = perm[b];
  const float lam = lmda[b];
  const float oml = 1.0f - lam;

  for (int e = tid; e < 1024; e += 256) {
    W1[e] = wht[b  * 1536 + 512 + e] * lam;
    W2[e] = wht[pb * 1536 + 512 + e] * oml;
  }
  if (tid < 32) {
    int ch1 = b * 64 + 32 + tid, ch2 = pb * 64 + 32 + tid;
    mu1[tid] = mu[ch1];
    mu2[tid] = mu[ch2];
    rs1[tid] = rsig[ch1];
    mm[tid]  = lam * med[ch1] + oml * med[ch2];
  }
  __syncthreads();

  const int p = blockIdx.x * 512 + tid * 2;
  const float* xb1 = x + (((size_t)(b  * 64 + 32)) << 14) + p;
  const float* xb2 = x + (((size_t)(pb * 64 + 32)) << 14) + p;
  float* ob = out + (((size_t)(b * 64 + 32)) << 14) + p;

  f2 xv1[32], xv2[32];
  #pragma unroll
  for (int d = 0; d < 32; ++d) xv1[d] = *reinterpret_cast<const f2*>(xb1 + ((size_t)d << 14));
  #pragma unroll
  for (int d = 0; d < 32; ++d) xv2[d] = *reinterpret_cast<const f2*>(xb2 + ((size_t)d << 14));
  #pragma unroll
  for (int d = 0; d < 32; ++d) { xv1[d] -= mu1[d]; xv2[d] -= mu2[d]; }

  f2 acc[32] = {};
  #pragma unroll
  for (int d = 0; d < 32; ++d) {
    #pragma unroll
    for (int c = 0; c < 32; ++c) {
      acc[c] += W1[d * 32 + c] * xv1[d];
      acc[c] += W2[d * 32 + c] * xv2[d];
    }
  }
  #pragma unroll
  for (int c = 0; c < 32; ++c) {
    f2 v = xv1[c] * rs1[c] * acc[c] + mm[c];
    __builtin_nontemporal_store(v, reinterpret_cast<f2*>(ob + ((size_t)c << 14)));
  }
}

extern "C" void kernel_launch(void* const* d_in, const int* in_sizes, int n_in,
                              void* d_out, int out_size, void* d_ws, size_t ws_size,
                              hipStream_t stream) {
  const float* x    = (const float*)d_in[0];
  const float* lmda = (const float*)d_in[1];
  const int*   perm = (const int*)d_in[2];
  float* out = (float*)d_out;
  float* ws  = (float*)d_ws;

  float* mu     = ws;
  float* rsig   = ws + 2048;
  float* med    = ws + 4096;
  float* wht    = ws + 6144;
  float* rspart = ws + 55296;
  float* gpart  = ws + 88064;

  gram_kernel<16><<<dim3(16, 2, 32), 256, 0, stream>>>(x, gpart, rspart);
  gram_kernel<32><<<dim3(16, 1, 32), 256, 0, stream>>>(x, gpart, rspart);

  stats_kernel<<<2048, 256, 0, stream>>>(x, med);

  ns_all<<<96, 256, 0, stream>>>(gpart, rspart, mu, rsig, wht);

  apply16<<<dim3(32, 2, 32), 256, 0, stream>>>(x, lmda, perm, mu, rsig, med, wht, out);
  apply32<<<dim3(32, 1, 32), 256, 0, stream>>>(x, lmda, perm, mu, rsig, med, wht, out);
}

// Round 18
// 212.198 us; speedup vs baseline: 1.2160x; 1.0556x over previous
//
#include <hip/hip_runtime.h>
#include <hip/hip_fp16.h>

#define HWPIX 16384

typedef _Float16 h2 __attribute__((ext_vector_type(2)));
typedef int v2i __attribute__((ext_vector_type(2)));
typedef float f2 __attribute__((ext_vector_type(2)));
typedef float f4 __attribute__((ext_vector_type(4)));

// ---------------------------------------------------------------------------
// ws layout (floats) — NO memset required (all slots fully overwritten):
//   mu     [2048]     @ 0       (ns_all)
//   rsig   [2048]     @ 2048    (ns_all)
//   med    [2048]     @ 4096    (stats)
//   wht    [49152]    @ 6144    (ns_all)
//   rspart [16*2048]  @ 55296   (gram partial row sums, plain stores)
//   gpart  [16*49152] @ 88064   (gram partials per k-chunk, plain stores)
// ---------------------------------------------------------------------------

template<int J>
__device__ inline unsigned shfl_xor_u(unsigned v, int lane) {
  if constexpr (J == 1)
    return (unsigned)__builtin_amdgcn_mov_dpp((int)v, 0xB1, 0xF, 0xF, true);   // quad_perm 1,0,3,2
  else if constexpr (J == 2)
    return (unsigned)__builtin_amdgcn_mov_dpp((int)v, 0x4E, 0xF, 0xF, true);   // quad_perm 2,3,0,1
  else if constexpr (J == 4)
    return (unsigned)__builtin_amdgcn_ds_swizzle((int)v, 0x101F);
  else if constexpr (J == 8)
    return (unsigned)__builtin_amdgcn_ds_swizzle((int)v, 0x201F);
  else if constexpr (J == 16)
    return (unsigned)__builtin_amdgcn_ds_swizzle((int)v, 0x401F);
  else {
#if __has_builtin(__builtin_amdgcn_permlane32_swap)
    // VALU cross-half swap: res0 upper half = v lower half; res1 lower = v upper.
    v2i r = __builtin_amdgcn_permlane32_swap((int)v, (int)v, false, false);
    return (lane & 32) ? (unsigned)r[0] : (unsigned)r[1];
#else
    return (unsigned)__shfl_xor((int)v, 32);
#endif
  }
}

__device__ inline unsigned pk_min(unsigned a, unsigned b) {
  h2 x = __builtin_bit_cast(h2, a), y = __builtin_bit_cast(h2, b);
  return __builtin_bit_cast(unsigned, __builtin_elementwise_min(x, y));
}
__device__ inline unsigned pk_max(unsigned a, unsigned b) {
  h2 x = __builtin_bit_cast(h2, a), y = __builtin_bit_cast(h2, b);
  return __builtin_bit_cast(unsigned, __builtin_elementwise_max(x, y));
}

__device__ inline unsigned pack2(float x, float y) {
  h2 p = {(_Float16)x, (_Float16)y};
  return __builtin_bit_cast(unsigned, p);
}

// DPP-based 64-lane max reduction step (VALU only, no LDS pipe).
template<int CTRL>
__device__ inline unsigned dppmax(unsigned m) {
  unsigned t = (unsigned)__builtin_amdgcn_update_dpp((int)m, (int)m, CTRL, 0xF, 0xF, false);
  return pk_max(m, t);
}

template<int K, int J, int Q>
__device__ inline void bstep(unsigned (&v0)[Q], unsigned (&v1)[Q], const int lane) {
  const bool sel0 = (((lane & J) == 0) == ((lane & K) == 0));
  const int i1 = lane + 64;
  const bool sel1 = (((i1 & J) == 0) == ((i1 & K) == 0));
  unsigned pv[Q];
  #pragma unroll
  for (int q = 0; q < Q; ++q) pv[q] = shfl_xor_u<J>(v0[q], lane);
  #pragma unroll
  for (int q = 0; q < Q; ++q)
    v0[q] = sel0 ? pk_min(v0[q], pv[q]) : pk_max(v0[q], pv[q]);
  #pragma unroll
  for (int q = 0; q < Q; ++q) pv[q] = shfl_xor_u<J>(v1[q], lane);
  #pragma unroll
  for (int q = 0; q < Q; ++q)
    v1[q] = sel1 ? pk_min(v1[q], pv[q]) : pk_max(v1[q], pv[q]);
  if constexpr (J > 1) bstep<K, J / 2, Q>(v0, v1, lane);
}

// Lower median (rank 63 of 128) per packed column. Stages k=2..64 make the
// sequence bitonic (asc 0-63, desc 64-127); min(v0,v1) isolates the 64
// smallest as a set; their max (DPP reduce -> lane 63) is sorted[63].
template<int Q>
__device__ inline void median128h_low(unsigned (&v0)[Q], unsigned (&v1)[Q],
                                      unsigned (&m)[Q], const int lane) {
  bstep<2, 1, Q>(v0, v1, lane);
  bstep<4, 2, Q>(v0, v1, lane);
  bstep<8, 4, Q>(v0, v1, lane);
  bstep<16, 8, Q>(v0, v1, lane);
  bstep<32, 16, Q>(v0, v1, lane);
  bstep<64, 32, Q>(v0, v1, lane);
  #pragma unroll
  for (int q = 0; q < Q; ++q) m[q] = pk_min(v0[q], v1[q]);
  #pragma unroll
  for (int q = 0; q < Q; ++q) m[q] = dppmax<0x111>(m[q]);  // row_shr:1
  #pragma unroll
  for (int q = 0; q < Q; ++q) m[q] = dppmax<0x112>(m[q]);  // row_shr:2
  #pragma unroll
  for (int q = 0; q < Q; ++q) m[q] = dppmax<0x114>(m[q]);  // row_shr:4
  #pragma unroll
  for (int q = 0; q < Q; ++q) m[q] = dppmax<0x118>(m[q]);  // row_shr:8
  #pragma unroll
  for (int q = 0; q < Q; ++q) m[q] = dppmax<0x142>(m[q]);  // row_bcast:15
  #pragma unroll
  for (int q = 0; q < Q; ++q) m[q] = dppmax<0x143>(m[q]);  // row_bcast:31 -> lane 63
}

template<int CTRL>
__device__ inline float fmax_dpp(float m) {
  float t = __builtin_bit_cast(float,
      __builtin_amdgcn_update_dpp(__builtin_bit_cast(int, m),
                                  __builtin_bit_cast(int, m), CTRL, 0xF, 0xF, false));
  return fmaxf(m, t);
}

// fp32 lower-median-of-128; result valid in lane 63.
__device__ inline float median128f_low(float v0, float v1, const int lane) {
  #pragma unroll
  for (int k = 2; k <= 64; k <<= 1) {
    #pragma unroll
    for (int j = k >> 1; j > 0; j >>= 1) {
      const bool sel0 = (((lane & j) == 0) == ((lane & k) == 0));
      const int i1 = lane + 64;
      const bool sel1 = (((i1 & j) == 0) == ((i1 & k) == 0));
      float pv = __shfl_xor(v0, j);
      v0 = sel0 ? fminf(v0, pv) : fmaxf(v0, pv);
      float pw = __shfl_xor(v1, j);
      v1 = sel1 ? fminf(v1, pw) : fmaxf(v1, pw);
    }
  }
  float m = fminf(v0, v1);
  m = fmax_dpp<0x111>(m); m = fmax_dpp<0x112>(m); m = fmax_dpp<0x114>(m);
  m = fmax_dpp<0x118>(m); m = fmax_dpp<0x142>(m); m = fmax_dpp<0x143>(m);
  return m;  // lane 63
}

// Median-only kernel, LDS-tile-free: lane l of wave w loads floats
// [w*32, w*32+32) of rows l and l+64 directly (full 128B line per row),
// packs to fp16x2 in registers, runs two 16-column sort batches.
// One block per (b,c), 256 threads (4 waves x 32 columns).
__global__ __launch_bounds__(256) void stats_kernel(const float* __restrict__ x,
                                                    float* __restrict__ med) {
  __shared__ float colmed[128];

  const int bc = blockIdx.x;
  const int tid = threadIdx.x;
  const int lane = tid & 63;
  const int wid  = tid >> 6;          // 0..3
  const float* rowA = x + (size_t)bc * HWPIX + (size_t)lane * 128 + wid * 32;
  const float* rowB = rowA + (size_t)64 * 128;

  unsigned a[16], b[16];              // 32 columns packed, rows lane / lane+64
  #pragma unroll
  for (int i = 0; i < 8; ++i) {
    f4 va = *reinterpret_cast<const f4*>(rowA + i * 4);
    f4 vb = *reinterpret_cast<const f4*>(rowB + i * 4);
    a[2 * i]     = pack2(va.x, va.y);
    a[2 * i + 1] = pack2(va.z, va.w);
    b[2 * i]     = pack2(vb.x, vb.y);
    b[2 * i + 1] = pack2(vb.z, vb.w);
  }

  #pragma unroll
  for (int t = 0; t < 2; ++t) {
    unsigned v0[8], v1[8], m[8];
    #pragma unroll
    for (int q = 0; q < 8; ++q) { v0[q] = a[t * 8 + q]; v1[q] = b[t * 8 + q]; }
    median128h_low<8>(v0, v1, m, lane);
    if (lane == 63) {
      const int base = wid * 32 + t * 16;
      #pragma unroll
      for (int q = 0; q < 8; ++q) {
        h2 mv = __builtin_bit_cast(h2, m[q]);
        colmed[base + 2 * q]     = (float)mv.x;
        colmed[base + 2 * q + 1] = (float)mv.y;
      }
    }
  }
  __syncthreads();
  if (wid == 0) {
    float m = median128f_low(colmed[lane], colmed[lane + 64], lane);
    if (lane == 63) med[bc] = m;
  }
}

// Gram partials + per-channel row-sum partials; plain stores, no atomics.
// grid (16, ngroups, 32); k-chunk = 1024 pixels. Separate kernels per CG so
// each gets its own register budget (grid-fusing them was a 3x regression).
// BT = threads per block (gram32 uses 512 to double per-CU wave count).
template<int CG, int BT>
__global__ __launch_bounds__(BT) void gram_kernel(const float* __restrict__ x,
                                                  float* __restrict__ gpart,
                                                  float* __restrict__ rspart) {
  constexpr int QT   = CG / 4;
  constexpr int TPG  = QT * QT;       // threads per gram replica
  constexpr int PQ   = BT / TPG;      // pixel groups
  constexpr int SUBP = 256 / PQ;      // pixels per group per sub-chunk
  constexpr int THR  = BT / CG;       // threads per row for rowsum
  constexpr int PERR = 256 / THR;     // floats per thread per row per sub-chunk
  __shared__ float tile[CG][260];

  const int b = blockIdx.z;
  const int g = blockIdx.y;
  const int s    = (CG == 16) ? g * 16  : 32;
  const int goff = (CG == 16) ? g * 256 : 512;
  const int chunk = blockIdx.x;
  const int k0 = chunk * 1024;
  const int tid = threadIdx.x;
  const int pq = tid / TPG;
  const int t  = tid % TPG;
  const int ty = t / QT, tx = t % QT;
  const int r0 = ty * 4, c0 = tx * 4;
  const int rrow = tid / THR;
  const int rseg = tid % THR;

  const float* xb = x + (((size_t)(b * 64 + s)) << 14) + k0;
  float acc[4][4] = {};
  float rsum = 0.f;

  for (int sc = 0; sc < 4; ++sc) {
    #pragma unroll
    for (int v = tid; v < CG * 64; v += BT) {
      int r = v >> 6;
      int p4 = (v & 63) * 4;
      *reinterpret_cast<float4*>(&tile[r][p4]) =
          *reinterpret_cast<const float4*>(xb + ((size_t)r << 14) + sc * 256 + p4);
    }
    __syncthreads();
    const int pb0 = pq * SUBP;
    #pragma unroll
    for (int p = pb0; p < pb0 + SUBP; p += 4) {
      float4 a[4], bb[4];
      #pragma unroll
      for (int i = 0; i < 4; ++i) a[i]  = *reinterpret_cast<const float4*>(&tile[r0 + i][p]);
      #pragma unroll
      for (int i = 0; i < 4; ++i) bb[i] = *reinterpret_cast<const float4*>(&tile[c0 + i][p]);
      #pragma unroll
      for (int i = 0; i < 4; ++i)
        #pragma unroll
        for (int j = 0; j < 4; ++j)
          acc[i][j] += a[i].x * bb[j].x + a[i].y * bb[j].y +
                       a[i].z * bb[j].z + a[i].w * bb[j].w;
    }
    // per-channel sum of this 256-px sub-chunk (reads tile inside barrier window)
    #pragma unroll
    for (int i = 0; i < PERR / 4; ++i) {
      const float4 v = *reinterpret_cast<const float4*>(&tile[rrow][rseg * PERR + i * 4]);
      rsum += v.x + v.y + v.z + v.w;
    }
    __syncthreads();
  }

  #pragma unroll
  for (int j = 1; j < THR; j <<= 1) rsum += __shfl_xor(rsum, j);
  if (rseg == 0) rspart[chunk * 2048 + b * 64 + s + rrow] = rsum;

  float* scratch = reinterpret_cast<float*>(tile);
  #pragma unroll
  for (int i = 0; i < 4; ++i)
    #pragma unroll
    for (int j = 0; j < 4; ++j)
      scratch[(t * PQ + pq) * 16 + i * 4 + j] = acc[i][j];
  __syncthreads();
  if (pq == 0) {
    float* gp = gpart + (size_t)(chunk * 32 + b) * 1536 + goff;
    #pragma unroll
    for (int i = 0; i < 4; ++i)
      #pragma unroll
      for (int j = 0; j < 4; ++j) {
        float v = 0.f;
        for (int q = 0; q < PQ; ++q) v += scratch[(t * PQ + q) * 16 + i * 4 + j];
        gp[(r0 + i) * CG + (c0 + j)] = v;
      }
  }
}

// ------------- Newton-Schulz inverse matrix sqrt (fused 16/32) -------------
template<int CG>
__device__ __forceinline__ void ns_impl(const float* __restrict__ gpart,
                                        const float* __restrict__ rspart,
                                        float* __restrict__ mu,
                                        float* __restrict__ rsig,
                                        float* __restrict__ wht,
                                        const int b, const int g, char* smem) {
  constexpr int NE = CG * CG;
  constexpr int PADC = CG + 4;
  constexpr int MS = CG * PADC;
  float* Y0 = (float*)smem;
  float* Z0 = Y0 + MS;
  float* Y1 = Z0 + MS;
  float* Z1 = Y1 + MS;
  float* T  = Z1 + MS;
  float* red = T + MS;

  const int s    = (CG == 16) ? g * 16  : 32;
  const int goff = (CG == 16) ? g * 256 : 512;
  const int tid = threadIdx.x;
  const float invHW = (float)(1.0 / (16384.0 + 1e-6));

  for (int e = tid; e < NE; e += 256) {
    int r = e / CG, c = e % CG;
    float v = 0.f;
    #pragma unroll
    for (int ch = 0; ch < 16; ++ch)
      v += gpart[(size_t)(ch * 32 + b) * 1536 + goff + e];
    T[r * PADC + c] = v;
  }
  __syncthreads();

  if (tid < CG) {
    float rs = 0.f;
    #pragma unroll
    for (int ch = 0; ch < 16; ++ch) rs += rspart[ch * 2048 + b * 64 + s + tid];
    const float diag = T[tid * PADC + tid];
    const float mean = rs * (1.0f / HWPIX);
    const float var = (diag - rs * mean) / (float)(HWPIX - 1);  // ddof=1
    mu[b * 64 + s + tid] = mean;
    rsig[b * 64 + s + tid] = rsqrtf(var + 1e-6f);
  }
  __syncthreads();

  float ssq = 0.f;
  for (int e = tid; e < NE; e += 256) {
    int r = e / CG, c = e % CG;
    float v = T[r * PADC + c] * invHW + ((r == c) ? 0.001002f : 0.0f);
    T[r * PADC + c] = v;
    ssq += v * v;
  }
  red[tid] = ssq;
  __syncthreads();
  for (int off = 128; off > 0; off >>= 1) {
    if (tid < off) red[tid] += red[tid + off];
    __syncthreads();
  }
  const float cn = sqrtf(red[0]);
  const float icn = 1.0f / cn;
  for (int e = tid; e < NE; e += 256) {
    int r = e / CG, c = e % CG;
    Y0[r * PADC + c] = T[r * PADC + c] * icn;
    Z0[r * PADC + c] = (r == c) ? 1.0f : 0.0f;
  }
  __syncthreads();

  constexpr int ACT = NE / 4;
  const int r  = tid / (CG / 4);
  const int c0 = (tid % (CG / 4)) * 4;

  for (int it = 0; it < 12; ++it) {
    float* Yi = (it & 1) ? Y1 : Y0;
    float* Zi = (it & 1) ? Z1 : Z0;
    float* Yo = (it & 1) ? Y0 : Y1;
    float* Zo = (it & 1) ? Z0 : Z1;
    if (tid < ACT) {
      float ax = 0.f, ay = 0.f, az = 0.f, aw = 0.f;
      #pragma unroll
      for (int k = 0; k < CG; ++k) {
        float zr = Zi[r * PADC + k];
        const float4 yk = *reinterpret_cast<const float4*>(&Yi[k * PADC + c0]);
        ax += zr * yk.x; ay += zr * yk.y; az += zr * yk.z; aw += zr * yk.w;
      }
      float4 tv;
      tv.x = ((r == c0 + 0) ? 3.f : 0.f) - ax;
      tv.y = ((r == c0 + 1) ? 3.f : 0.f) - ay;
      tv.z = ((r == c0 + 2) ? 3.f : 0.f) - az;
      tv.w = ((r == c0 + 3) ? 3.f : 0.f) - aw;
      *reinterpret_cast<float4*>(&T[r * PADC + c0]) = tv;
    }
    __syncthreads();
    if (tid < ACT) {
      float yx = 0.f, yy = 0.f, yz = 0.f, yw = 0.f;
      float zx = 0.f, zy = 0.f, zz = 0.f, zw = 0.f;
      #pragma unroll
      for (int k = 0; k < CG; ++k) {
        float yr = Yi[r * PADC + k];
        float tr = T[r * PADC + k];
        const float4 tk = *reinterpret_cast<const float4*>(&T[k * PADC + c0]);
        const float4 zk = *reinterpret_cast<const float4*>(&Zi[k * PADC + c0]);
        yx += yr * tk.x; yy += yr * tk.y; yz += yr * tk.z; yw += yr * tk.w;
        zx += tr * zk.x; zy += tr * zk.y; zz += tr * zk.z; zw += tr * zk.w;
      }
      *reinterpret_cast<float4*>(&Yo[r * PADC + c0]) =
          make_float4(0.5f * yx, 0.5f * yy, 0.5f * yz, 0.5f * yw);
      *reinterpret_cast<float4*>(&Zo[r * PADC + c0]) =
          make_float4(0.5f * zx, 0.5f * zy, 0.5f * zz, 0.5f * zw);
    }
    __syncthreads();
  }

  const float wscale = rsqrtf(cn);
  for (int e = tid; e < NE; e += 256) {
    int r2 = e / CG, c2 = e % CG;
    wht[b * 1536 + goff + e] = Z0[r2 * PADC + c2] * wscale;
  }
}

__global__ __launch_bounds__(256) void ns_all(const float* __restrict__ gpart,
                                              const float* __restrict__ rspart,
                                              float* __restrict__ mu,
                                              float* __restrict__ rsig,
                                              float* __restrict__ wht) {
  __shared__ __align__(16) char smem[5 * 32 * 36 * 4 + 1024];
  const int bid = blockIdx.x;
  if (bid < 64) ns_impl<16>(gpart, rspart, mu, rsig, wht, bid >> 1, bid & 1, smem);
  else          ns_impl<32>(gpart, rspart, mu, rsig, wht, bid - 64, 0, smem);
}

// --------------- fused whitening-apply + mix + normalize -------------------
// apply16: CG=16, P=2 pixels/thread (round-14 best config).
__global__ __launch_bounds__(256, 4) void apply16(
    const float* __restrict__ x, const float* __restrict__ lmda,
    const int* __restrict__ perm, const float* __restrict__ mu,
    const float* __restrict__ rsig, const float* __restrict__ med,
    const float* __restrict__ wht, float* __restrict__ out) {
  __shared__ float W1[256], W2[256];
  __shared__ float mu1[16], mu2[16], rs1[16], mm[16];

  const int b = blockIdx.z;
  const int g = blockIdx.y;
  const int s = g * 16, goff = g * 256;
  const int tid = threadIdx.x;
  const int pb = perm[b];
  const float lam = lmda[b];
  const float oml = 1.0f - lam;

  if (tid < 256) {
    W1[tid] = wht[b  * 1536 + goff + tid] * lam;
    W2[tid] = wht[pb * 1536 + goff + tid] * oml;
  }
  if (tid < 16) {
    int ch1 = b * 64 + s + tid, ch2 = pb * 64 + s + tid;
    mu1[tid] = mu[ch1];
    mu2[tid] = mu[ch2];
    rs1[tid] = rsig[ch1];
    mm[tid]  = lam * med[ch1] + oml * med[ch2];
  }
  __syncthreads();

  const int p = blockIdx.x * 512 + tid * 2;
  const float* xb1 = x + (((size_t)(b  * 64 + s)) << 14) + p;
  const float* xb2 = x + (((size_t)(pb * 64 + s)) << 14) + p;
  float* ob = out + (((size_t)(b * 64 + s)) << 14) + p;

  f2 xv1[16], xv2[16];
  #pragma unroll
  for (int d = 0; d < 16; ++d) xv1[d] = *reinterpret_cast<const f2*>(xb1 + ((size_t)d << 14));
  #pragma unroll
  for (int d = 0; d < 16; ++d) xv2[d] = *reinterpret_cast<const f2*>(xb2 + ((size_t)d << 14));
  #pragma unroll
  for (int d = 0; d < 16; ++d) { xv1[d] -= mu1[d]; xv2[d] -= mu2[d]; }

  f2 acc[16] = {};
  #pragma unroll
  for (int d = 0; d < 16; ++d) {
    #pragma unroll
    for (int c = 0; c < 16; ++c) {
      acc[c] += W1[d * 16 + c] * xv1[d];
      acc[c] += W2[d * 16 + c] * xv2[d];
    }
  }
  #pragma unroll
  for (int c = 0; c < 16; ++c) {
    f2 v = xv1[c] * rs1[c] * acc[c] + mm[c];
    __builtin_nontemporal_store(v, reinterpret_cast<f2*>(ob + ((size_t)c << 14)));
  }
}

// apply32: monolithic CG=32, P=2 pixels/thread — each x element read exactly
// once (the c-half split doubled HBM reads and was 2.7x slower).
__global__ __launch_bounds__(256, 2) void apply32(
    const float* __restrict__ x, const float* __restrict__ lmda,
    const int* __restrict__ perm, const float* __restrict__ mu,
    const float* __restrict__ rsig, const float* __restrict__ med,
    const float* __restrict__ wht, float* __restrict__ out) {
  __shared__ float W1[1024], W2[1024];
  __shared__ float mu1[32], mu2[32], rs1[32], mm[32];

  const int b = blockIdx.z;
  const int tid = threadIdx.x;
  const int pb = perm[b];
  const float lam = lmda[b];
  const float oml = 1.0f - lam;

  for (int e = tid; e < 1024; e += 256) {
    W1[e] = wht[b  * 1536 + 512 + e] * lam;
    W2[e] = wht[pb * 1536 + 512 + e] * oml;
  }
  if (tid < 32) {
    int ch1 = b * 64 + 32 + tid, ch2 = pb * 64 + 32 + tid;
    mu1[tid] = mu[ch1];
    mu2[tid] = mu[ch2];
    rs1[tid] = rsig[ch1];
    mm[tid]  = lam * med[ch1] + oml * med[ch2];
  }
  __syncthreads();

  const int p = blockIdx.x * 512 + tid * 2;
  const float* xb1 = x + (((size_t)(b  * 64 + 32)) << 14) + p;
  const float* xb2 = x + (((size_t)(pb * 64 + 32)) << 14) + p;
  float* ob = out + (((size_t)(b * 64 + 32)) << 14) + p;

  f2 xv1[32], xv2[32];
  #pragma unroll
  for (int d = 0; d < 32; ++d) xv1[d] = *reinterpret_cast<const f2*>(xb1 + ((size_t)d << 14));
  #pragma unroll
  for (int d = 0; d < 32; ++d) xv2[d] = *reinterpret_cast<const f2*>(xb2 + ((size_t)d << 14));
  #pragma unroll
  for (int d = 0; d < 32; ++d) { xv1[d] -= mu1[d]; xv2[d] -= mu2[d]; }

  f2 acc[32] = {};
  #pragma unroll
  for (int d = 0; d < 32; ++d) {
    #pragma unroll
    for (int c = 0; c < 32; ++c) {
      acc[c] += W1[d * 32 + c] * xv1[d];
      acc[c] += W2[d * 32 + c] * xv2[d];
    }
  }
  #pragma unroll
  for (int c = 0; c < 32; ++c) {
    f2 v = xv1[c] * rs1[c] * acc[c] + mm[c];
    __builtin_nontemporal_store(v, reinterpret_cast<f2*>(ob + ((size_t)c << 14)));
  }
}

extern "C" void kernel_launch(void* const* d_in, const int* in_sizes, int n_in,
                              void* d_out, int out_size, void* d_ws, size_t ws_size,
                              hipStream_t stream) {
  const float* x    = (const float*)d_in[0];
  const float* lmda = (const float*)d_in[1];
  const int*   perm = (const int*)d_in[2];
  float* out = (float*)d_out;
  float* ws  = (float*)d_ws;

  float* mu     = ws;
  float* rsig   = ws + 2048;
  float* med    = ws + 4096;
  float* wht    = ws + 6144;
  float* rspart = ws + 55296;
  float* gpart  = ws + 88064;

  // stats first: its full read of x warms L3 for the gram passes.
  stats_kernel<<<2048, 256, 0, stream>>>(x, med);

  gram_kernel<16, 256><<<dim3(16, 2, 32), 256, 0, stream>>>(x, gpart, rspart);
  gram_kernel<32, 512><<<dim3(16, 1, 32), 512, 0, stream>>>(x, gpart, rspart);

  ns_all<<<96, 256, 0, stream>>>(gpart, rspart, mu, rsig, wht);

  apply16<<<dim3(32, 2, 32), 256, 0, stream>>>(x, lmda, perm, mu, rsig, med, wht, out);
  apply32<<<dim3(32, 1, 32), 256, 0, stream>>>(x, lmda, perm, mu, rsig, med, wht, out);
}